// Round 5
// baseline (1528.144 us; speedup 1.0000x reference)
//
#include <hip/hip_runtime.h>
#include <math.h>

#define NCHUNK 22
#define SEQLEN 600
#define BN_EPS 1e-5f
#define Y1S 156              // y1p row stride (u32)

// ws offsets (4-byte units)
#define OFF_W1F    0         // 1024   u32 : conv1 B dup-frags [ph2][pat2][lane][r]
#define OFF_W2F    1024      // 32768  u32 : conv2 B dup-frags [s32][nt2][pat2][lane][r]
#define OFF_W3F    33792     // 102400 u32 : conv3 B dup-frags [s50][nt4][pat2][lane][r]
#define OFF_WQKVF  136192    // 98304  u32 : Wqkv B-frags [h8][ks2][nt12][hl2][lane][r] (R4 layout)
#define OFF_WFCT   234496    // 32768  f32 : Wfc transposed [j][d]
#define OFF_WOUTT  267264    // 4096   f32 : Wout transposed [k][d]
#define OFF_FEAT   271360    // 2*B*22*64 u32 (PACKED hi|lo)
#define REPACK_N   271360

typedef short bf16x8 __attribute__((ext_vector_type(8)));
typedef float f32x4 __attribute__((ext_vector_type(4)));

#if __has_builtin(__builtin_amdgcn_perm)
#define PERM_HI(r0, r1) __builtin_amdgcn_perm((r1), (r0), 0x05040100u)
#define PERM_LO(r0, r1) __builtin_amdgcn_perm((r1), (r0), 0x07060302u)
#else
#define PERM_HI(r0, r1) (((r0) & 0xFFFFu) | ((r1) << 16))
#define PERM_LO(r0, r1) (((r0) >> 16) | ((r1) & 0xFFFF0000u))
#endif

__device__ __forceinline__ float swishf(float z) {
    return z / (1.f + __expf(-z));
}
__device__ __forceinline__ unsigned short bf16_rne(float f) {
    unsigned int u = __float_as_uint(f);
    return (unsigned short)((u + 0x7FFFu + ((u >> 16) & 1u)) >> 16);
}
__device__ __forceinline__ float bf16_tof(unsigned short h) {
    return __uint_as_float(((unsigned int)h) << 16);
}
// packed u32: low16 = hi-bf16, high16 = lo-bf16 (residual)
__device__ __forceinline__ unsigned int pack_hl(float f) {
    unsigned int u = __float_as_uint(f);
    unsigned int h = (u + 0x7FFFu + ((u >> 16) & 1u)) >> 16;
    float r = f - __uint_as_float(h << 16);
    unsigned int v = __float_as_uint(r);
    unsigned int l = (v + 0x7FFFu + ((v >> 16) & 1u)) >> 16;
    return h | (l << 16);
}
// B word for the dup scheme: both 16-bit slots = bf16_hi(f) (pat=0) or bf16_lo(f) (pat=1)
__device__ __forceinline__ unsigned int dup_word(float f, int pat) {
    unsigned short h = bf16_rne(f);
    unsigned short v = pat ? bf16_rne(f - bf16_tof(h)) : h;
    return (unsigned int)v | ((unsigned int)v << 16);
}
// R4-style B word: (bf16 part of f0, bf16 part of f1)
__device__ __forceinline__ unsigned int frag_word(float f0, float f1, int hl) {
    unsigned short h0 = bf16_rne(f0), h1 = bf16_rne(f1);
    if (hl == 0) return (unsigned int)h0 | ((unsigned int)h1 << 16);
    unsigned short l0 = bf16_rne(f0 - bf16_tof(h0));
    unsigned short l1 = bf16_rne(f1 - bf16_tof(h1));
    return (unsigned int)l0 | ((unsigned int)l1 << 16);
}
// hi/lo bf16x8 A-fragments from 8 packed u32 (R4 path, used by MHA QKV only)
__device__ __forceinline__ void frag_from_packed(const unsigned int* p, bf16x8& h8, bf16x8& l8) {
    unsigned int r0 = p[0], r1 = p[1], r2 = p[2], r3 = p[3];
    unsigned int r4 = p[4], r5 = p[5], r6 = p[6], r7 = p[7];
    union U { unsigned int w[4]; bf16x8 v; } H, L;
    H.w[0] = PERM_HI(r0, r1); H.w[1] = PERM_HI(r2, r3);
    H.w[2] = PERM_HI(r4, r5); H.w[3] = PERM_HI(r6, r7);
    L.w[0] = PERM_LO(r0, r1); L.w[1] = PERM_LO(r2, r3);
    L.w[2] = PERM_LO(r4, r5); L.w[3] = PERM_LO(r6, r7);
    h8 = H.v; l8 = L.v;
}

__global__ __launch_bounds__(256) void repack_kernel(
    const float* __restrict__ w1, const float* __restrict__ w2, const float* __restrict__ w3,
    const float* __restrict__ Wq, const float* __restrict__ Wk, const float* __restrict__ Wv,
    const float* __restrict__ Wfc, const float* __restrict__ Wout,
    float* __restrict__ ws)
{
    int tid = blockIdx.x * 256 + threadIdx.x;
    unsigned int* wsu = (unsigned int*)ws;
    if (tid < 1024) {                        // conv1 B: k = ph*16 + lg*4 + r, col = ci = li
        int r = tid & 3, lane = (tid >> 2) & 63, pat = (tid >> 8) & 1, ph = (tid >> 9) & 1;
        int li = lane & 15, lg = lane >> 4;
        int k = ph * 16 + lg * 4 + r;
        float f = (k < 26) ? w1[li * 26 + k] : 0.f;
        wsu[OFF_W1F + tid] = dup_word(f, pat);
    }
    int t2 = tid - 1024;
    if (t2 >= 0 && t2 < 32768) {             // conv2 B: s=(ci,ph), k = (s&1)*16+lg*4+r
        int r = t2 & 3, lane = (t2 >> 2) & 63, pat = (t2 >> 8) & 1, nt = (t2 >> 9) & 1, s = t2 >> 10;
        int li = lane & 15, lg = lane >> 4;
        int co = nt * 16 + li, ci = s >> 1;
        int k = (s & 1) * 16 + lg * 4 + r;
        float f = (k < 26) ? w2[co * 416 + ci * 26 + k] : 0.f;
        wsu[OFF_W2F + t2] = dup_word(f, pat);
    }
    int t3 = tid - 33792;
    if (t3 >= 0 && t3 < 102400) {            // conv3 B: pos = s*16+lg*4+r, pos = q*32+ci
        int r = t3 & 3, lane = (t3 >> 2) & 63, pat = (t3 >> 8) & 1, nt = (t3 >> 9) & 3, s = t3 >> 11;
        int li = lane & 15, lg = lane >> 4;
        int co = nt * 16 + li;
        int pos = s * 16 + lg * 4 + r;
        float f = w3[co * 800 + (pos & 31) * 25 + (pos >> 5)];
        wsu[OFF_W3F + t3] = dup_word(f, pat);
    }
    int t4 = tid - 136192;
    if (t4 >= 0 && t4 < 98304) {             // Wqkv B-frags (R4 layout, unchanged)
        int r = t4 & 3, l = (t4 >> 2) & 63, hl = (t4 >> 8) & 1;
        int rest = t4 >> 9;                  // 0..191
        int nt = rest % 12, rest2 = rest / 12;
        int ks = rest2 & 1, h = rest2 >> 1;
        int n = nt * 16 + (l & 15);
        int mat = n >> 6, e = n & 63;
        int d0 = ks * 32 + (l >> 4) * 8 + 2 * r;
        const float* W = (mat == 0) ? Wq : (mat == 1) ? Wk : Wv;
        float f0 = W[h * 4096 + e * 64 + d0];
        float f1 = W[h * 4096 + e * 64 + d0 + 1];
        wsu[OFF_WQKVF + t4] = frag_word(f0, f1, hl);
    }
    int t5 = tid - 234496;
    if (t5 >= 0 && t5 < 32768) {             // wfcT[j*64+d] = Wfc[d][j]
        int d = t5 & 63, j = t5 >> 6;
        ws[OFF_WFCT + t5] = Wfc[d * 512 + j];
    }
    int t6 = tid - 267264;
    if (t6 >= 0 && t6 < 4096) {              // woutT[k*64+d] = Wout[d][k]
        int d = t6 & 63, k = t6 >> 6;
        ws[OFF_WOUTT + t6] = Wout[d * 64 + k];
    }
}

// One block = one 5-chunk tile. All three convs on MFMA with the dup-B scheme:
// A operands are raw packed (hi|lo) u32 streams, B supplies dup(w_hi) then
// dup(w_lo) -> full 4-term split product, zero perms.
__global__ __launch_bounds__(256, 4) void encoder_kernel(
    const float* __restrict__ audio1, const float* __restrict__ audio2,
    const float* __restrict__ b1, const float* __restrict__ g1, const float* __restrict__ be1,
    const float* __restrict__ m1, const float* __restrict__ v1,
    const float* __restrict__ b2, const float* __restrict__ g2, const float* __restrict__ be2,
    const float* __restrict__ m2, const float* __restrict__ v2,
    const float* __restrict__ b3, const float* __restrict__ g3, const float* __restrict__ be3,
    const float* __restrict__ m3, const float* __restrict__ v3,
    float* __restrict__ ws, int B)
{
    __shared__ __align__(16) unsigned int smem[10012];
    unsigned int* a_p = smem;                // 192 packed audio
    unsigned int* w1f = smem + 192;          // 1024 conv1 B-frags
    unsigned int* w2f = smem + 1216;         // 2 x 1024 dbuf conv2 B-frags
    unsigned int* y1p = smem + 3264;         // 16 x 156 (+8 pad)
    unsigned int* y2p = smem + 5768;         // 5 x 804
    float* A_s  = (float*)(smem + 9788);     // 112
    float* Bc_s = (float*)(smem + 9900);     // 112

    int t = threadIdx.x;
    int blk = blockIdx.x;
    int seq = blk / 5, tile = blk - seq * 5;
    int tc = (tile == 4) ? 2 : 5;
    int nq = 25 * tc;                        // 125 or 50
    int ny1 = nq + 25;
    int na = nq + 50;
    const unsigned int* wsu = (const unsigned int*)ws;
    int lane = t & 63, wid = t >> 6;
    int li = lane & 15, lg = lane >> 4;

    const float* audio = (seq < B ? audio1 + (size_t)seq * SEQLEN
                                  : audio2 + (size_t)(seq - B) * SEQLEN) + tile * 125;
    if (t < 192) a_p[t] = (t < na) ? pack_hl(audio[t]) : 0u;
    *(uint4*)(w1f + t * 4) = *(const uint4*)(wsu + OFF_W1F + t * 4);
    *(uint4*)(w2f + t * 4) = *(const uint4*)(wsu + OFF_W2F + t * 4);   // stage step 0
    if (t < 16)       { float A = g1[t] * rsqrtf(v1[t] + BN_EPS); A_s[t] = A; Bc_s[t] = (b1[t] - m1[t]) * A + be1[t]; }
    else if (t < 48)  { int i = t - 16; float A = g2[i] * rsqrtf(v2[i] + BN_EPS); A_s[t] = A; Bc_s[t] = (b2[i] - m2[i]) * A + be2[i]; }
    else if (t < 112) { int i = t - 48; float A = g3[i] * rsqrtf(v3[i] + BN_EPS); A_s[t] = A; Bc_s[t] = (b3[i] - m3[i]) * A + be3[i]; }
    __syncthreads();

    // ---- conv1 MFMA: D[p][ci], Mtiles strided over waves ----
    {
        int nMt1 = (ny1 + 15) >> 4;
        float Ai = A_s[li], Bi = Bc_s[li];
        for (int mt = wid; mt < nMt1; mt += 4) {
            f32x4 acc = {0.f, 0.f, 0.f, 0.f};
            #pragma unroll
            for (int ph = 0; ph < 2; ++ph) {
                const unsigned int* ap = a_p + mt * 16 + li + ph * 16 + lg * 4;
                union { unsigned int w[4]; bf16x8 v; } A;
                A.w[0] = ap[0]; A.w[1] = ap[1]; A.w[2] = ap[2]; A.w[3] = ap[3];
                bf16x8 b0 = *(const bf16x8*)(w1f + ((ph * 2 + 0) * 64 + lane) * 4);
                bf16x8 b1 = *(const bf16x8*)(w1f + ((ph * 2 + 1) * 64 + lane) * 4);
                acc = __builtin_amdgcn_mfma_f32_16x16x32_bf16(A.v, b0, acc, 0, 0, 0);
                acc = __builtin_amdgcn_mfma_f32_16x16x32_bf16(A.v, b1, acc, 0, 0, 0);
            }
            #pragma unroll
            for (int r = 0; r < 4; ++r) {
                int p = mt * 16 + lg * 4 + r;
                if (p < ny1) y1p[li * Y1S + p] = pack_hl(swishf(fmaf(acc[r], Ai, Bi)));
            }
        }
        for (int i = t; i < 16 * Y1S; i += 256) {
            int p = i % Y1S;
            if (p >= ny1) y1p[i] = 0u;
        }
        if (t < 8) y1p[2496 + t] = 0u;       // pad beyond last row
    }

    // ---- conv2 MFMA: 32 steps (16 ci x 2 pos-halves), dup-B, LDS dbuf ----
    int nmt = (nq + 15) >> 4;                // 8 or 4
    f32x4 c00 = {0.f,0.f,0.f,0.f}, c01 = c00, c10 = c00, c11 = c00;
    int q0 = wid * 16 + li;
    int q1 = (wid + 4) * 16 + li;
    for (int s = 0; s < 32; ++s) {
        __syncthreads();
        if (s < 31) {
            uint4 v = *(const uint4*)(wsu + OFF_W2F + (s + 1) * 1024 + t * 4);
            *(uint4*)(w2f + ((s + 1) & 1) * 1024 + t * 4) = v;
        }
        const unsigned int* cur = w2f + (s & 1) * 1024;
        bf16x8 b00 = *(const bf16x8*)(cur + lane * 4);          // nt0 dup(hi)
        bf16x8 b01 = *(const bf16x8*)(cur + 256 + lane * 4);    // nt0 dup(lo)
        bf16x8 b10 = *(const bf16x8*)(cur + 512 + lane * 4);    // nt1 dup(hi)
        bf16x8 b11 = *(const bf16x8*)(cur + 768 + lane * 4);    // nt1 dup(lo)
        const unsigned int* yr = y1p + (s >> 1) * Y1S + (s & 1) * 16 + lg * 4;
        union { unsigned int w[4]; bf16x8 v; } A0, A1;
        A0.w[0] = yr[q0]; A0.w[1] = yr[q0 + 1]; A0.w[2] = yr[q0 + 2]; A0.w[3] = yr[q0 + 3];
        c00 = __builtin_amdgcn_mfma_f32_16x16x32_bf16(A0.v, b00, c00, 0, 0, 0);
        c00 = __builtin_amdgcn_mfma_f32_16x16x32_bf16(A0.v, b01, c00, 0, 0, 0);
        c01 = __builtin_amdgcn_mfma_f32_16x16x32_bf16(A0.v, b10, c01, 0, 0, 0);
        c01 = __builtin_amdgcn_mfma_f32_16x16x32_bf16(A0.v, b11, c01, 0, 0, 0);
        if (nmt == 8) {
            A1.w[0] = yr[q1]; A1.w[1] = yr[q1 + 1]; A1.w[2] = yr[q1 + 2]; A1.w[3] = yr[q1 + 3];
            c10 = __builtin_amdgcn_mfma_f32_16x16x32_bf16(A1.v, b00, c10, 0, 0, 0);
            c10 = __builtin_amdgcn_mfma_f32_16x16x32_bf16(A1.v, b01, c10, 0, 0, 0);
            c11 = __builtin_amdgcn_mfma_f32_16x16x32_bf16(A1.v, b10, c11, 0, 0, 0);
            c11 = __builtin_amdgcn_mfma_f32_16x16x32_bf16(A1.v, b11, c11, 0, 0, 0);
        }
    }
    // epilogue: bn + swish -> y2p packed [cc*804 + q'*32 + co]
    {
        float A0v = A_s[16 + li], B0v = Bc_s[16 + li];
        float A1v = A_s[32 + li], B1v = Bc_s[32 + li];
        #pragma unroll
        for (int r = 0; r < 4; ++r) {
            int q = wid * 16 + lg * 4 + r;
            if (q < nq) {
                int cc = q / 25, qp = q - cc * 25;
                y2p[cc * 804 + qp * 32 + li]      = pack_hl(swishf(fmaf(c00[r], A0v, B0v)));
                y2p[cc * 804 + qp * 32 + 16 + li] = pack_hl(swishf(fmaf(c01[r], A1v, B1v)));
            }
        }
        if (nmt == 8) {
            #pragma unroll
            for (int r = 0; r < 4; ++r) {
                int q = (wid + 4) * 16 + lg * 4 + r;
                if (q < nq) {
                    int cc = q / 25, qp = q - cc * 25;
                    y2p[cc * 804 + qp * 32 + li]      = pack_hl(swishf(fmaf(c10[r], A0v, B0v)));
                    y2p[cc * 804 + qp * 32 + 16 + li] = pack_hl(swishf(fmaf(c11[r], A1v, B1v)));
                }
            }
        }
    }
    __syncthreads();

    // ---- conv3 MFMA: wave = Ntile, 50 steps, dup-B reg-prefetched from L2 ----
    {
        const uint4* w3f4 = (const uint4*)(wsu + OFF_W3F);
        f32x4 acc3 = {0.f, 0.f, 0.f, 0.f};
        uint4 b0n = w3f4[((0 * 4 + wid) * 2 + 0) * 64 + lane];
        uint4 b1n = w3f4[((0 * 4 + wid) * 2 + 1) * 64 + lane];
        for (int s = 0; s < 50; ++s) {
            uint4 b0c = b0n, b1c = b1n;
            if (s < 49) {
                b0n = w3f4[(((s + 1) * 4 + wid) * 2 + 0) * 64 + lane];
                b1n = w3f4[(((s + 1) * 4 + wid) * 2 + 1) * 64 + lane];
            }
            union { unsigned int w[4]; bf16x8 v; } A;
            if (li < tc) {
                const unsigned int* yp = y2p + li * 804 + s * 16 + lg * 4;
                A.w[0] = yp[0]; A.w[1] = yp[1]; A.w[2] = yp[2]; A.w[3] = yp[3];
            } else { A.w[0] = 0u; A.w[1] = 0u; A.w[2] = 0u; A.w[3] = 0u; }
            bf16x8 b0 = *(const bf16x8*)&b0c;
            bf16x8 b1 = *(const bf16x8*)&b1c;
            acc3 = __builtin_amdgcn_mfma_f32_16x16x32_bf16(A.v, b0, acc3, 0, 0, 0);
            acc3 = __builtin_amdgcn_mfma_f32_16x16x32_bf16(A.v, b1, acc3, 0, 0, 0);
        }
        int co = wid * 16 + li;
        float A3 = A_s[48 + co], B3 = Bc_s[48 + co];
        unsigned int* featp = (unsigned int*)ws + OFF_FEAT;
        #pragma unroll
        for (int r = 0; r < 4; ++r) {
            int cc = lg * 4 + r;
            if (cc < tc)
                featp[((size_t)(seq * NCHUNK + tile * 5 + cc)) * 64 + co]
                    = pack_hl(swishf(fmaf(acc3[r], A3, B3)));
        }
    }
}

// One block per sequence. QKV via MFMA (R4-proven path, feat arrives packed);
// mean folded before fc (pooled attention); scores/softmax scalar.
__global__ __launch_bounds__(256, 4) void mha_kernel(
    const float* __restrict__ ws,
    const float* __restrict__ bq, const float* __restrict__ bk, const float* __restrict__ bv,
    const float* __restrict__ bfc, const float* __restrict__ bout,
    float* __restrict__ out, int B)
{
    __shared__ float smem[7760];
    unsigned int* f_p = (unsigned int*)smem;  // 32 x 68 packed (rows 22..31 zero)
    float* q_s    = smem + 2176;  // 22 x 64
    float* k_s    = smem + 3584;  // 22 x 65
    float* v_s    = smem + 5014;  // 22 x 64
    float* s_s    = smem + 6422;  // 22 x 22
    float* abar_s = smem + 6906;  // 22
    float* obar_s = smem + 6928;  // 8 x 64
    float* fred   = smem + 7440;  // 4 x 64
    float* fcbar_s= smem + 7696;  // 64

    int t = threadIdx.x, b = blockIdx.x;
    int lane = t & 63, wid = t >> 6;
    int li = lane & 15, lg = lane >> 4;
    const unsigned int* featp = (const unsigned int*)ws + OFF_FEAT + (size_t)b * 1408;
    for (int i = t; i < 1408; i += 256) f_p[(i >> 6) * 68 + (i & 63)] = featp[i];
    for (int i = 1496 + t; i < 2176; i += 256) f_p[i] = 0u;
    __syncthreads();

    bf16x8 fah[2][2], fal[2][2];
    #pragma unroll
    for (int mt = 0; mt < 2; ++mt)
        #pragma unroll
        for (int ks = 0; ks < 2; ++ks)
            frag_from_packed(f_p + (mt * 16 + li) * 68 + ks * 32 + lg * 8,
                             fah[mt][ks], fal[mt][ks]);

    const uint4* wqkvf4 = (const uint4*)((const unsigned int*)ws + OFF_WQKVF);

    for (int h = 0; h < 8; ++h) {
        for (int j = 0; j < 3; ++j) {
            int nt = wid * 3 + j;
            f32x4 a0 = {0.f,0.f,0.f,0.f}, a1 = a0;
            #pragma unroll
            for (int ks = 0; ks < 2; ++ks) {
                uint4 bh4 = wqkvf4[(((h * 2 + ks) * 12 + nt) * 2 + 0) * 64 + lane];
                uint4 bl4 = wqkvf4[(((h * 2 + ks) * 12 + nt) * 2 + 1) * 64 + lane];
                bf16x8 bh = *(const bf16x8*)&bh4;
                bf16x8 bl = *(const bf16x8*)&bl4;
                a0 = __builtin_amdgcn_mfma_f32_16x16x32_bf16(fah[0][ks], bh, a0, 0, 0, 0);
                a0 = __builtin_amdgcn_mfma_f32_16x16x32_bf16(fal[0][ks], bh, a0, 0, 0, 0);
                a0 = __builtin_amdgcn_mfma_f32_16x16x32_bf16(fah[0][ks], bl, a0, 0, 0, 0);
                a1 = __builtin_amdgcn_mfma_f32_16x16x32_bf16(fah[1][ks], bh, a1, 0, 0, 0);
                a1 = __builtin_amdgcn_mfma_f32_16x16x32_bf16(fal[1][ks], bh, a1, 0, 0, 0);
                a1 = __builtin_amdgcn_mfma_f32_16x16x32_bf16(fah[1][ks], bl, a1, 0, 0, 0);
            }
            int mat = nt >> 2;
            int e = (nt & 3) * 16 + li;
            float* dst; int stride; float bias;
            if (mat == 0)      { dst = q_s; stride = 64; bias = bq[h * 64 + e]; }
            else if (mat == 1) { dst = k_s; stride = 65; bias = bk[h * 64 + e]; }
            else               { dst = v_s; stride = 64; bias = bv[h * 64 + e]; }
            #pragma unroll
            for (int r = 0; r < 4; ++r) {
                int row0 = lg * 4 + r;
                dst[row0 * stride + e] = a0[r] + bias;
                int row1 = 16 + row0;
                if (row1 < 22) dst[row1 * stride + e] = a1[r] + bias;
            }
        }
        __syncthreads();
        for (int o = t; o < 484; o += 256) {
            int s = o / 22, u = o - s * 22;
            float acc = 0.f;
            #pragma unroll 16
            for (int d = 0; d < 64; ++d) acc = fmaf(q_s[s * 64 + d], k_s[u * 65 + d], acc);
            s_s[s * 22 + u] = acc;
        }
        __syncthreads();
        if (t < 22) {
            float m = -1e30f;
            #pragma unroll
            for (int j2 = 0; j2 < 22; ++j2) m = fmaxf(m, s_s[t * 22 + j2]);
            float sum = 0.f;
            #pragma unroll
            for (int j2 = 0; j2 < 22; ++j2) { float ev = __expf(s_s[t * 22 + j2] - m); s_s[t * 22 + j2] = ev; sum += ev; }
            float rr = 1.f / sum;
            #pragma unroll
            for (int j2 = 0; j2 < 22; ++j2) s_s[t * 22 + j2] *= rr;
        }
        __syncthreads();
        if (t < 22) {
            float a = 0.f;
            #pragma unroll
            for (int s = 0; s < 22; ++s) a += s_s[s * 22 + t];
            abar_s[t] = a * (1.f / 22.f);
        }
        __syncthreads();
        if (t < 64) {
            float acc = 0.f;
            #pragma unroll
            for (int u = 0; u < 22; ++u) acc = fmaf(abar_s[u], v_s[u * 64 + t], acc);
            obar_s[h * 64 + t] = acc;
        }
        __syncthreads();
    }
    {
        int d = t & 63, part = t >> 6;
        const float* wfc = ws + OFF_WFCT + d;
        float acc = 0.f;
        for (int j = part * 128; j < part * 128 + 128; ++j)
            acc = fmaf(obar_s[j], wfc[j * 64], acc);
        fred[part * 64 + d] = acc;
    }
    __syncthreads();
    if (t < 64) fcbar_s[t] = bfc[t] + fred[t] + fred[64 + t] + fred[128 + t] + fred[192 + t];
    __syncthreads();
    if (t < 64) {
        const float* woutT = ws + OFF_WOUTT;
        float acc = bout[t];
        #pragma unroll 16
        for (int k = 0; k < 64; ++k) acc = fmaf(fcbar_s[k], woutT[k * 64 + t], acc);
        out[(size_t)b * 64 + t] = acc;
    }
}

extern "C" void kernel_launch(void* const* d_in, const int* in_sizes, int n_in,
                              void* d_out, int out_size, void* d_ws, size_t ws_size,
                              hipStream_t stream) {
    const float* audio1 = (const float*)d_in[0];
    const float* audio2 = (const float*)d_in[1];
    const float* w1   = (const float*)d_in[2];
    const float* b1   = (const float*)d_in[3];
    const float* g1   = (const float*)d_in[4];
    const float* be1  = (const float*)d_in[5];
    const float* m1   = (const float*)d_in[6];
    const float* v1   = (const float*)d_in[7];
    const float* w2   = (const float*)d_in[8];
    const float* b2   = (const float*)d_in[9];
    const float* g2   = (const float*)d_in[10];
    const float* be2  = (const float*)d_in[11];
    const float* m2   = (const float*)d_in[12];
    const float* v2   = (const float*)d_in[13];
    const float* w3   = (const float*)d_in[14];
    const float* b3   = (const float*)d_in[15];
    const float* g3   = (const float*)d_in[16];
    const float* be3  = (const float*)d_in[17];
    const float* m3   = (const float*)d_in[18];
    const float* v3   = (const float*)d_in[19];
    const float* Wq   = (const float*)d_in[20];
    const float* bq   = (const float*)d_in[21];
    const float* Wk   = (const float*)d_in[22];
    const float* bk   = (const float*)d_in[23];
    const float* Wv   = (const float*)d_in[24];
    const float* bv   = (const float*)d_in[25];
    const float* Wfc  = (const float*)d_in[26];
    const float* bfc  = (const float*)d_in[27];
    const float* Wout = (const float*)d_in[28];
    const float* bout = (const float*)d_in[29];

    float* ws  = (float*)d_ws;
    float* out = (float*)d_out;
    int B = in_sizes[0] / SEQLEN;   // 4096
    int nseq = 2 * B;

    repack_kernel<<<(REPACK_N + 255) / 256, 256, 0, stream>>>(w1, w2, w3, Wq, Wk, Wv, Wfc, Wout, ws);
    encoder_kernel<<<nseq * 5, 256, 0, stream>>>(audio1, audio2,
        b1, g1, be1, m1, v1,
        b2, g2, be2, m2, v2,
        b3, g3, be3, m3, v3,
        ws, B);
    mha_kernel<<<nseq, 256, 0, stream>>>(ws, bq, bk, bv, bfc, bout, out, B);
}

// Round 6
// 1266.486 us; speedup vs baseline: 1.2066x; 1.2066x over previous
//
#include <hip/hip_runtime.h>
#include <math.h>

#define NCHUNK 22
#define SEQLEN 600
#define BN_EPS 1e-5f
#define Y1S 164              // y1p row stride (u32); 164%32=4

// ws offsets (4-byte units)
#define OFF_W1F    0         // 1024   u32 : conv1 B dup-frags [ph2][pat2][lane][r]
#define OFF_W2F    1024      // 13312  u32 : conv2 32x32 B-frags [s26][hl2][lane][r4]
#define OFF_W3F    14336     // 51200  u32 : conv3 B-frags [s25][nt4][hl2][lane][r4]
#define OFF_WQKVF  65536     // 98304  u32 : Wqkv B-frags [h8][ks2][nt12][hl2][lane][r]
#define OFF_WFCT   163840    // 32768  f32 : Wfc transposed [j][d]
#define OFF_WOUTT  196608    // 4096   f32 : Wout transposed [k][d]
#define OFF_FEAT   200704    // 2*B*22*64 u32 (PACKED hi|lo)
#define REPACK_N   200704

typedef short bf16x8 __attribute__((ext_vector_type(8)));
typedef float f32x4 __attribute__((ext_vector_type(4)));
typedef float f32x16 __attribute__((ext_vector_type(16)));

#if __has_builtin(__builtin_amdgcn_perm)
#define PERM_HI(r0, r1) __builtin_amdgcn_perm((r1), (r0), 0x05040100u)
#define PERM_LO(r0, r1) __builtin_amdgcn_perm((r1), (r0), 0x07060302u)
#else
#define PERM_HI(r0, r1) (((r0) & 0xFFFFu) | ((r1) << 16))
#define PERM_LO(r0, r1) (((r0) >> 16) | ((r1) & 0xFFFF0000u))
#endif

__device__ __forceinline__ float swishf(float z) {
    return z / (1.f + __expf(-z));
}
__device__ __forceinline__ unsigned short bf16_rne(float f) {
    unsigned int u = __float_as_uint(f);
    return (unsigned short)((u + 0x7FFFu + ((u >> 16) & 1u)) >> 16);
}
__device__ __forceinline__ float bf16_tof(unsigned short h) {
    return __uint_as_float(((unsigned int)h) << 16);
}
// packed u32: low16 = hi-bf16, high16 = lo-bf16 (residual)
__device__ __forceinline__ unsigned int pack_hl(float f) {
    unsigned int u = __float_as_uint(f);
    unsigned int h = (u + 0x7FFFu + ((u >> 16) & 1u)) >> 16;
    float r = f - __uint_as_float(h << 16);
    unsigned int v = __float_as_uint(r);
    unsigned int l = (v + 0x7FFFu + ((v >> 16) & 1u)) >> 16;
    return h | (l << 16);
}
// dup-B word (conv1 only): both halves = bf16_hi(f) (pat=0) or bf16_lo(f) (pat=1)
__device__ __forceinline__ unsigned int dup_word(float f, int pat) {
    unsigned short h = bf16_rne(f);
    unsigned short v = pat ? bf16_rne(f - bf16_tof(h)) : h;
    return (unsigned int)v | ((unsigned int)v << 16);
}
// split B word: (bf16 part of f0, bf16 part of f1)
__device__ __forceinline__ unsigned int frag_word(float f0, float f1, int hl) {
    unsigned short h0 = bf16_rne(f0), h1 = bf16_rne(f1);
    if (hl == 0) return (unsigned int)h0 | ((unsigned int)h1 << 16);
    unsigned short l0 = bf16_rne(f0 - bf16_tof(h0));
    unsigned short l1 = bf16_rne(f1 - bf16_tof(h1));
    return (unsigned int)l0 | ((unsigned int)l1 << 16);
}
// hi/lo bf16x8 A-fragments from 8 packed u32 (contiguous)
__device__ __forceinline__ void frag_from_packed(const unsigned int* p, bf16x8& h8, bf16x8& l8) {
    unsigned int r0 = p[0], r1 = p[1], r2 = p[2], r3 = p[3];
    unsigned int r4 = p[4], r5 = p[5], r6 = p[6], r7 = p[7];
    union U { unsigned int w[4]; bf16x8 v; } H, L;
    H.w[0] = PERM_HI(r0, r1); H.w[1] = PERM_HI(r2, r3);
    H.w[2] = PERM_HI(r4, r5); H.w[3] = PERM_HI(r6, r7);
    L.w[0] = PERM_LO(r0, r1); L.w[1] = PERM_LO(r2, r3);
    L.w[2] = PERM_LO(r4, r5); L.w[3] = PERM_LO(r6, r7);
    h8 = H.v; l8 = L.v;
}
// hi/lo frags from 8 strided packed words (already loaded)
__device__ __forceinline__ void frag_from_words(
    unsigned int a0, unsigned int a1, unsigned int a2, unsigned int a3,
    unsigned int a4, unsigned int a5, unsigned int a6, unsigned int a7,
    bf16x8& h8, bf16x8& l8) {
    union U { unsigned int w[4]; bf16x8 v; } H, L;
    H.w[0] = PERM_HI(a0, a1); H.w[1] = PERM_HI(a2, a3);
    H.w[2] = PERM_HI(a4, a5); H.w[3] = PERM_HI(a6, a7);
    L.w[0] = PERM_LO(a0, a1); L.w[1] = PERM_LO(a2, a3);
    L.w[2] = PERM_LO(a4, a5); L.w[3] = PERM_LO(a6, a7);
    h8 = H.v; l8 = L.v;
}

__global__ __launch_bounds__(256) void repack_kernel(
    const float* __restrict__ w1, const float* __restrict__ w2, const float* __restrict__ w3,
    const float* __restrict__ Wq, const float* __restrict__ Wk, const float* __restrict__ Wv,
    const float* __restrict__ Wfc, const float* __restrict__ Wout,
    float* __restrict__ ws)
{
    int tid = blockIdx.x * 256 + threadIdx.x;
    unsigned int* wsu = (unsigned int*)ws;
    if (tid < 1024) {                        // conv1 dup-B: k-tap = ph*16 + lg*4 + r
        int r = tid & 3, lane = (tid >> 2) & 63, pat = (tid >> 8) & 1, ph = (tid >> 9) & 1;
        int li = lane & 15, lg = lane >> 4;
        int k = ph * 16 + lg * 4 + r;
        float f = (k < 26) ? w1[li * 26 + k] : 0.f;
        wsu[OFF_W1F + tid] = dup_word(f, pat);
    }
    int t2 = tid - 1024;
    if (t2 >= 0 && t2 < 13312) {             // conv2 32x32x16: step s = tap, slot = ci
        int r = t2 & 3, lane = (t2 >> 2) & 63, hl = (t2 >> 8) & 1, s = t2 >> 9;  // s 0..25
        int co = lane & 31;
        int ci0 = (lane >> 5) * 8;
        float f0 = w2[co * 416 + (ci0 + 2 * r) * 26 + s];
        float f1 = w2[co * 416 + (ci0 + 2 * r + 1) * 26 + s];
        wsu[OFF_W2F + t2] = frag_word(f0, f1, hl);
    }
    int t3 = tid - 14336;
    if (t3 >= 0 && t3 < 51200) {             // conv3 B-frags (R4 layout): k=j=q*32+ci
        int r = t3 & 3, l = (t3 >> 2) & 63, hl = (t3 >> 8) & 1;
        int nt = (t3 >> 9) & 3, s = t3 >> 11;
        int co = nt * 16 + (l & 15);
        int k0 = s * 32 + (l >> 4) * 8 + 2 * r;
        float f0 = w3[co * 800 + (k0 & 31) * 25 + (k0 >> 5)];
        float f1 = w3[co * 800 + ((k0 + 1) & 31) * 25 + ((k0 + 1) >> 5)];
        wsu[OFF_W3F + t3] = frag_word(f0, f1, hl);
    }
    int t4 = tid - 65536;
    if (t4 >= 0 && t4 < 98304) {             // Wqkv B-frags (R4 layout)
        int r = t4 & 3, l = (t4 >> 2) & 63, hl = (t4 >> 8) & 1;
        int rest = t4 >> 9;
        int nt = rest % 12, rest2 = rest / 12;
        int ks = rest2 & 1, h = rest2 >> 1;
        int n = nt * 16 + (l & 15);
        int mat = n >> 6, e = n & 63;
        int d0 = ks * 32 + (l >> 4) * 8 + 2 * r;
        const float* W = (mat == 0) ? Wq : (mat == 1) ? Wk : Wv;
        float f0 = W[h * 4096 + e * 64 + d0];
        float f1 = W[h * 4096 + e * 64 + d0 + 1];
        wsu[OFF_WQKVF + t4] = frag_word(f0, f1, hl);
    }
    int t5 = tid - 163840;
    if (t5 >= 0 && t5 < 32768) {             // wfcT[j*64+d] = Wfc[d][j]
        int d = t5 & 63, j = t5 >> 6;
        ws[OFF_WFCT + t5] = Wfc[d * 512 + j];
    }
    int t6 = tid - 196608;
    if (t6 >= 0 && t6 < 4096) {              // woutT[k*64+d] = Wout[d][k]
        int d = t6 & 63, k = t6 >> 6;
        ws[OFF_WOUTT + t6] = Wout[d * 64 + k];
    }
}

// One block = one 5-chunk tile. conv1: MFMA dup-B (R5-proven). conv2: 32x32x16
// MFMA, koff-major K (26 exact steps), split-3, 13 double-buffered B stages.
// conv3: 16x16x32 MFMA split-3 (R4-proven).
__global__ __launch_bounds__(256, 4) void encoder_kernel(
    const float* __restrict__ audio1, const float* __restrict__ audio2,
    const float* __restrict__ b1, const float* __restrict__ g1, const float* __restrict__ be1,
    const float* __restrict__ m1, const float* __restrict__ v1,
    const float* __restrict__ b2, const float* __restrict__ g2, const float* __restrict__ be2,
    const float* __restrict__ m2, const float* __restrict__ v2,
    const float* __restrict__ b3, const float* __restrict__ g3, const float* __restrict__ be3,
    const float* __restrict__ m3, const float* __restrict__ v3,
    float* __restrict__ ws, int B)
{
    __shared__ __align__(16) unsigned int smem[10132];
    unsigned int* a_p = smem;                // 192 packed audio
    unsigned int* w1f = smem + 192;          // 1024 conv1 B-frags
    unsigned int* w2f = smem + 1216;         // 2 x 1024 dbuf conv2 B-frag stages
    unsigned int* y1p = smem + 3264;         // 16 x 164 packed
    unsigned int* y2p = smem + 5888;         // 5 x 804 packed
    float* A_s  = (float*)(smem + 9908);     // 112
    float* Bc_s = (float*)(smem + 10020);    // 112

    int t = threadIdx.x;
    int blk = blockIdx.x;
    int seq = blk / 5, tile = blk - seq * 5;
    int tc = (tile == 4) ? 2 : 5;
    int nq = 25 * tc;                        // 125 or 50
    int ny1 = nq + 25;
    int na = nq + 50;
    const unsigned int* wsu = (const unsigned int*)ws;
    int lane = t & 63, wid = t >> 6;
    int li = lane & 15, lg = lane >> 4;

    const float* audio = (seq < B ? audio1 + (size_t)seq * SEQLEN
                                  : audio2 + (size_t)(seq - B) * SEQLEN) + tile * 125;
    if (t < 192) a_p[t] = (t < na) ? pack_hl(audio[t]) : 0u;
    *(uint4*)(w1f + t * 4) = *(const uint4*)(wsu + OFF_W1F + t * 4);
    *(uint4*)(w2f + t * 4) = *(const uint4*)(wsu + OFF_W2F + t * 4);   // stage 0 (steps 0,1)
    if (t < 16)       { float A = g1[t] * rsqrtf(v1[t] + BN_EPS); A_s[t] = A; Bc_s[t] = (b1[t] - m1[t]) * A + be1[t]; }
    else if (t < 48)  { int i = t - 16; float A = g2[i] * rsqrtf(v2[i] + BN_EPS); A_s[t] = A; Bc_s[t] = (b2[i] - m2[i]) * A + be2[i]; }
    else if (t < 112) { int i = t - 48; float A = g3[i] * rsqrtf(v3[i] + BN_EPS); A_s[t] = A; Bc_s[t] = (b3[i] - m3[i]) * A + be3[i]; }
    __syncthreads();

    // ---- conv1 MFMA (dup-B, R5-proven): D[p][ci], Mtiles strided over waves ----
    {
        int nMt1 = (ny1 + 15) >> 4;
        float Ai = A_s[li], Bi = Bc_s[li];
        for (int mt = wid; mt < nMt1; mt += 4) {
            f32x4 acc = {0.f, 0.f, 0.f, 0.f};
            #pragma unroll
            for (int ph = 0; ph < 2; ++ph) {
                const unsigned int* ap = a_p + mt * 16 + li + ph * 16 + lg * 4;
                union { unsigned int w[4]; bf16x8 v; } A;
                A.w[0] = ap[0]; A.w[1] = ap[1]; A.w[2] = ap[2]; A.w[3] = ap[3];
                bf16x8 b0 = *(const bf16x8*)(w1f + ((ph * 2 + 0) * 64 + lane) * 4);
                bf16x8 b1 = *(const bf16x8*)(w1f + ((ph * 2 + 1) * 64 + lane) * 4);
                acc = __builtin_amdgcn_mfma_f32_16x16x32_bf16(A.v, b0, acc, 0, 0, 0);
                acc = __builtin_amdgcn_mfma_f32_16x16x32_bf16(A.v, b1, acc, 0, 0, 0);
            }
            #pragma unroll
            for (int r = 0; r < 4; ++r) {
                int p = mt * 16 + lg * 4 + r;
                if (p < ny1) y1p[li * Y1S + p] = pack_hl(swishf(fmaf(acc[r], Ai, Bi)));
            }
        }
        for (int i = t; i < 16 * Y1S; i += 256) {   // zero tails (p >= ny1)
            int p = i % Y1S;
            if (p >= ny1) y1p[i] = 0u;
        }
    }

    // ---- conv2 MFMA 32x32x16: 26 steps (one tap each, slot = ci), split-3 ----
    {
        int row = wid * 32 + (lane & 31);            // output position q (M index)
        int ci0 = (lane >> 5) * 8;
        const unsigned int* ybase = y1p + ci0 * Y1S + row;
        f32x16 acc;
        #pragma unroll
        for (int r = 0; r < 16; ++r) acc[r] = 0.f;

        for (int stg = 0; stg < 13; ++stg) {
            __syncthreads();
            if (stg < 12) {
                uint4 v = *(const uint4*)(wsu + OFF_W2F + (stg + 1) * 1024 + t * 4);
                *(uint4*)(w2f + ((stg + 1) & 1) * 1024 + t * 4) = v;
            }
            const unsigned int* cur = w2f + (stg & 1) * 1024;
            #pragma unroll
            for (int half = 0; half < 2; ++half) {
                int s = stg * 2 + half;
                bf16x8 bh = *(const bf16x8*)(cur + half * 512 + lane * 4);
                bf16x8 bl = *(const bf16x8*)(cur + half * 512 + 256 + lane * 4);
                const unsigned int* yp = ybase + s;
                bf16x8 ah, al;
                frag_from_words(yp[0], yp[Y1S], yp[2 * Y1S], yp[3 * Y1S],
                                yp[4 * Y1S], yp[5 * Y1S], yp[6 * Y1S], yp[7 * Y1S],
                                ah, al);
                acc = __builtin_amdgcn_mfma_f32_32x32x16_bf16(ah, bh, acc, 0, 0, 0);
                acc = __builtin_amdgcn_mfma_f32_32x32x16_bf16(al, bh, acc, 0, 0, 0);
                acc = __builtin_amdgcn_mfma_f32_32x32x16_bf16(ah, bl, acc, 0, 0, 0);
            }
        }
        // epilogue: C col = lane&31 = co, row = (reg&3)+8*(reg>>2)+4*(lane>>5)
        int co = lane & 31;
        float Ac = A_s[16 + co], Bc = Bc_s[16 + co];
        int rbase = 4 * (lane >> 5) + wid * 32;
        #pragma unroll
        for (int reg = 0; reg < 16; ++reg) {
            int q = rbase + (reg & 3) + 8 * (reg >> 2);
            if (q < nq) {
                int cc = q / 25, qp = q - cc * 25;
                y2p[cc * 804 + qp * 32 + co] = pack_hl(swishf(fmaf(acc[reg], Ac, Bc)));
            }
        }
    }
    __syncthreads();

    // ---- conv3 MFMA 16x16x32 (R4-proven): wave = Ntile, 25 steps, split-3 ----
    {
        const uint4* w3f4 = (const uint4*)(wsu + OFF_W3F);
        f32x4 acc3 = {0.f, 0.f, 0.f, 0.f};
        uint4 bhn = w3f4[((0 * 4 + wid) * 2 + 0) * 64 + lane];
        uint4 bln = w3f4[((0 * 4 + wid) * 2 + 1) * 64 + lane];
        for (int s = 0; s < 25; ++s) {
            uint4 bhc = bhn, blc = bln;
            if (s < 24) {
                bhn = w3f4[(((s + 1) * 4 + wid) * 2 + 0) * 64 + lane];
                bln = w3f4[(((s + 1) * 4 + wid) * 2 + 1) * 64 + lane];
            }
            bf16x8 ah = {}, al = {};
            if (li < tc) frag_from_packed(y2p + li * 804 + s * 32 + lg * 8, ah, al);
            bf16x8 bh = *(const bf16x8*)&bhc;
            bf16x8 bl = *(const bf16x8*)&blc;
            acc3 = __builtin_amdgcn_mfma_f32_16x16x32_bf16(ah, bh, acc3, 0, 0, 0);
            acc3 = __builtin_amdgcn_mfma_f32_16x16x32_bf16(al, bh, acc3, 0, 0, 0);
            acc3 = __builtin_amdgcn_mfma_f32_16x16x32_bf16(ah, bl, acc3, 0, 0, 0);
        }
        int co = wid * 16 + li;
        float A3 = A_s[48 + co], B3 = Bc_s[48 + co];
        unsigned int* featp = (unsigned int*)ws + OFF_FEAT;
        #pragma unroll
        for (int r = 0; r < 4; ++r) {
            int cc = lg * 4 + r;
            if (cc < tc)
                featp[((size_t)(seq * NCHUNK + tile * 5 + cc)) * 64 + co]
                    = pack_hl(swishf(fmaf(acc3[r], A3, B3)));
        }
    }
}

// One block per sequence. QKV via MFMA (R4-proven, feat arrives packed);
// mean folded before fc (pooled attention); scores/softmax scalar.
__global__ __launch_bounds__(256, 4) void mha_kernel(
    const float* __restrict__ ws,
    const float* __restrict__ bq, const float* __restrict__ bk, const float* __restrict__ bv,
    const float* __restrict__ bfc, const float* __restrict__ bout,
    float* __restrict__ out, int B)
{
    __shared__ float smem[7760];
    unsigned int* f_p = (unsigned int*)smem;  // 32 x 68 packed (rows 22..31 zero)
    float* q_s    = smem + 2176;  // 22 x 64
    float* k_s    = smem + 3584;  // 22 x 65
    float* v_s    = smem + 5014;  // 22 x 64
    float* s_s    = smem + 6422;  // 22 x 22
    float* abar_s = smem + 6906;  // 22
    float* obar_s = smem + 6928;  // 8 x 64
    float* fred   = smem + 7440;  // 4 x 64
    float* fcbar_s= smem + 7696;  // 64

    int t = threadIdx.x, b = blockIdx.x;
    int lane = t & 63, wid = t >> 6;
    int li = lane & 15, lg = lane >> 4;
    const unsigned int* featp = (const unsigned int*)ws + OFF_FEAT + (size_t)b * 1408;
    for (int i = t; i < 1408; i += 256) f_p[(i >> 6) * 68 + (i & 63)] = featp[i];
    for (int i = 1496 + t; i < 2176; i += 256) f_p[i] = 0u;
    __syncthreads();

    bf16x8 fah[2][2], fal[2][2];
    #pragma unroll
    for (int mt = 0; mt < 2; ++mt)
        #pragma unroll
        for (int ks = 0; ks < 2; ++ks)
            frag_from_packed(f_p + (mt * 16 + li) * 68 + ks * 32 + lg * 8,
                             fah[mt][ks], fal[mt][ks]);

    const uint4* wqkvf4 = (const uint4*)((const unsigned int*)ws + OFF_WQKVF);

    for (int h = 0; h < 8; ++h) {
        for (int j = 0; j < 3; ++j) {
            int nt = wid * 3 + j;
            f32x4 a0 = {0.f,0.f,0.f,0.f}, a1 = a0;
            #pragma unroll
            for (int ks = 0; ks < 2; ++ks) {
                uint4 bh4 = wqkvf4[(((h * 2 + ks) * 12 + nt) * 2 + 0) * 64 + lane];
                uint4 bl4 = wqkvf4[(((h * 2 + ks) * 12 + nt) * 2 + 1) * 64 + lane];
                bf16x8 bh = *(const bf16x8*)&bh4;
                bf16x8 bl = *(const bf16x8*)&bl4;
                a0 = __builtin_amdgcn_mfma_f32_16x16x32_bf16(fah[0][ks], bh, a0, 0, 0, 0);
                a0 = __builtin_amdgcn_mfma_f32_16x16x32_bf16(fal[0][ks], bh, a0, 0, 0, 0);
                a0 = __builtin_amdgcn_mfma_f32_16x16x32_bf16(fah[0][ks], bl, a0, 0, 0, 0);
                a1 = __builtin_amdgcn_mfma_f32_16x16x32_bf16(fah[1][ks], bh, a1, 0, 0, 0);
                a1 = __builtin_amdgcn_mfma_f32_16x16x32_bf16(fal[1][ks], bh, a1, 0, 0, 0);
                a1 = __builtin_amdgcn_mfma_f32_16x16x32_bf16(fah[1][ks], bl, a1, 0, 0, 0);
            }
            int mat = nt >> 2;
            int e = (nt & 3) * 16 + li;
            float* dst; int stride; float bias;
            if (mat == 0)      { dst = q_s; stride = 64; bias = bq[h * 64 + e]; }
            else if (mat == 1) { dst = k_s; stride = 65; bias = bk[h * 64 + e]; }
            else               { dst = v_s; stride = 64; bias = bv[h * 64 + e]; }
            #pragma unroll
            for (int r = 0; r < 4; ++r) {
                int row0 = lg * 4 + r;
                dst[row0 * stride + e] = a0[r] + bias;
                int row1 = 16 + row0;
                if (row1 < 22) dst[row1 * stride + e] = a1[r] + bias;
            }
        }
        __syncthreads();
        for (int o = t; o < 484; o += 256) {
            int s = o / 22, u = o - s * 22;
            float acc = 0.f;
            #pragma unroll 16
            for (int d = 0; d < 64; ++d) acc = fmaf(q_s[s * 64 + d], k_s[u * 65 + d], acc);
            s_s[s * 22 + u] = acc;
        }
        __syncthreads();
        if (t < 22) {
            float m = -1e30f;
            #pragma unroll
            for (int j2 = 0; j2 < 22; ++j2) m = fmaxf(m, s_s[t * 22 + j2]);
            float sum = 0.f;
            #pragma unroll
            for (int j2 = 0; j2 < 22; ++j2) { float ev = __expf(s_s[t * 22 + j2] - m); s_s[t * 22 + j2] = ev; sum += ev; }
            float rr = 1.f / sum;
            #pragma unroll
            for (int j2 = 0; j2 < 22; ++j2) s_s[t * 22 + j2] *= rr;
        }
        __syncthreads();
        if (t < 22) {
            float a = 0.f;
            #pragma unroll
            for (int s = 0; s < 22; ++s) a += s_s[s * 22 + t];
            abar_s[t] = a * (1.f / 22.f);
        }
        __syncthreads();
        if (t < 64) {
            float acc = 0.f;
            #pragma unroll
            for (int u = 0; u < 22; ++u) acc = fmaf(abar_s[u], v_s[u * 64 + t], acc);
            obar_s[h * 64 + t] = acc;
        }
        __syncthreads();
    }
    {
        int d = t & 63, part = t >> 6;
        const float* wfc = ws + OFF_WFCT + d;
        float acc = 0.f;
        for (int j = part * 128; j < part * 128 + 128; ++j)
            acc = fmaf(obar_s[j], wfc[j * 64], acc);
        fred[part * 64 + d] = acc;
    }
    __syncthreads();
    if (t < 64) fcbar_s[t] = bfc[t] + fred[t] + fred[64 + t] + fred[128 + t] + fred[192 + t];
    __syncthreads();
    if (t < 64) {
        const float* woutT = ws + OFF_WOUTT;
        float acc = bout[t];
        #pragma unroll 16
        for (int k = 0; k < 64; ++k) acc = fmaf(fcbar_s[k], woutT[k * 64 + t], acc);
        out[(size_t)b * 64 + t] = acc;
    }
}

extern "C" void kernel_launch(void* const* d_in, const int* in_sizes, int n_in,
                              void* d_out, int out_size, void* d_ws, size_t ws_size,
                              hipStream_t stream) {
    const float* audio1 = (const float*)d_in[0];
    const float* audio2 = (const float*)d_in[1];
    const float* w1   = (const float*)d_in[2];
    const float* b1   = (const float*)d_in[3];
    const float* g1   = (const float*)d_in[4];
    const float* be1  = (const float*)d_in[5];
    const float* m1   = (const float*)d_in[6];
    const float* v1   = (const float*)d_in[7];
    const float* w2   = (const float*)d_in[8];
    const float* b2   = (const float*)d_in[9];
    const float* g2   = (const float*)d_in[10];
    const float* be2  = (const float*)d_in[11];
    const float* m2   = (const float*)d_in[12];
    const float* v2   = (const float*)d_in[13];
    const float* w3   = (const float*)d_in[14];
    const float* b3   = (const float*)d_in[15];
    const float* g3   = (const float*)d_in[16];
    const float* be3  = (const float*)d_in[17];
    const float* m3   = (const float*)d_in[18];
    const float* v3   = (const float*)d_in[19];
    const float* Wq   = (const float*)d_in[20];
    const float* bq   = (const float*)d_in[21];
    const float* Wk   = (const float*)d_in[22];
    const float* bk   = (const float*)d_in[23];
    const float* Wv   = (const float*)d_in[24];
    const float* bv   = (const float*)d_in[25];
    const float* Wfc  = (const float*)d_in[26];
    const float* bfc  = (const float*)d_in[27];
    const float* Wout = (const float*)d_in[28];
    const float* bout = (const float*)d_in[29];

    float* ws  = (float*)d_ws;
    float* out = (float*)d_out;
    int B = in_sizes[0] / SEQLEN;   // 4096
    int nseq = 2 * B;

    repack_kernel<<<(REPACK_N + 255) / 256, 256, 0, stream>>>(w1, w2, w3, Wq, Wk, Wv, Wfc, Wout, ws);
    encoder_kernel<<<nseq * 5, 256, 0, stream>>>(audio1, audio2,
        b1, g1, be1, m1, v1,
        b2, g2, be2, m2, v2,
        b3, g3, be3, m3, v3,
        ws, B);
    mha_kernel<<<nseq, 256, 0, stream>>>(ws, bq, bk, bv, bfc, bout, out, B);
}

// Round 7
// 1197.886 us; speedup vs baseline: 1.2757x; 1.0573x over previous
//
#include <hip/hip_runtime.h>
#include <math.h>

#define NCHUNK 22
#define SEQLEN 600
#define BN_EPS 1e-5f

// ws offsets (4-byte units)
#define OFF_W1F    0         // 1024   u32 : conv1 B dup-frags [ph2][pat2][lane][r]
#define OFF_W2F    1024      // 13312  u32 : conv2 32x32 B-frags [s26][hl2][lane][r4]
#define OFF_W3F    14336     // 51200  u32 : conv3 B-frags [s25][nt4][hl2][lane][r4]
#define OFF_WQKVF  65536     // 98304  u32 : Wqkv B-frags [h8][ks2][nt12][hl2][lane][r]
#define OFF_WCOMB  163840    // 32768  f32 : Wcomb[j][k] = sum_d Wfc[d][j]*Wout[k][d]
#define OFF_CBIAS  196608    // 64     f32 : bout + bfc @ Wout^T
#define OFF_FEAT   196672    // 2*B*22*64 u32 (PACKED hi|lo)
#define REPACK_N   196672

typedef short bf16x8 __attribute__((ext_vector_type(8)));
typedef float f32x4 __attribute__((ext_vector_type(4)));
typedef float f32x16 __attribute__((ext_vector_type(16)));

#if __has_builtin(__builtin_amdgcn_perm)
#define PERM_HI(r0, r1) __builtin_amdgcn_perm((r1), (r0), 0x05040100u)
#define PERM_LO(r0, r1) __builtin_amdgcn_perm((r1), (r0), 0x07060302u)
#else
#define PERM_HI(r0, r1) (((r0) & 0xFFFFu) | ((r1) << 16))
#define PERM_LO(r0, r1) (((r0) >> 16) | ((r1) & 0xFFFF0000u))
#endif

__device__ __forceinline__ float swishf(float z) {
    return z / (1.f + __expf(-z));
}
__device__ __forceinline__ unsigned short bf16_rne(float f) {
    unsigned int u = __float_as_uint(f);
    return (unsigned short)((u + 0x7FFFu + ((u >> 16) & 1u)) >> 16);
}
__device__ __forceinline__ float bf16_tof(unsigned short h) {
    return __uint_as_float(((unsigned int)h) << 16);
}
// packed u32: low16 = hi-bf16, high16 = lo-bf16 (residual)
__device__ __forceinline__ unsigned int pack_hl(float f) {
    unsigned int u = __float_as_uint(f);
    unsigned int h = (u + 0x7FFFu + ((u >> 16) & 1u)) >> 16;
    float r = f - __uint_as_float(h << 16);
    unsigned int v = __float_as_uint(r);
    unsigned int l = (v + 0x7FFFu + ((v >> 16) & 1u)) >> 16;
    return h | (l << 16);
}
// dup-B word (conv1): both halves = bf16_hi(f) (pat=0) or bf16_lo(f) (pat=1)
__device__ __forceinline__ unsigned int dup_word(float f, int pat) {
    unsigned short h = bf16_rne(f);
    unsigned short v = pat ? bf16_rne(f - bf16_tof(h)) : h;
    return (unsigned int)v | ((unsigned int)v << 16);
}
// split B word: (bf16 part of f0, bf16 part of f1)
__device__ __forceinline__ unsigned int frag_word(float f0, float f1, int hl) {
    unsigned short h0 = bf16_rne(f0), h1 = bf16_rne(f1);
    if (hl == 0) return (unsigned int)h0 | ((unsigned int)h1 << 16);
    unsigned short l0 = bf16_rne(f0 - bf16_tof(h0));
    unsigned short l1 = bf16_rne(f1 - bf16_tof(h1));
    return (unsigned int)l0 | ((unsigned int)l1 << 16);
}
// hi/lo bf16x8 A-fragments from 8 packed u32 (contiguous; MHA only)
__device__ __forceinline__ void frag_from_packed(const unsigned int* p, bf16x8& h8, bf16x8& l8) {
    unsigned int r0 = p[0], r1 = p[1], r2 = p[2], r3 = p[3];
    unsigned int r4 = p[4], r5 = p[5], r6 = p[6], r7 = p[7];
    union U { unsigned int w[4]; bf16x8 v; } H, L;
    H.w[0] = PERM_HI(r0, r1); H.w[1] = PERM_HI(r2, r3);
    H.w[2] = PERM_HI(r4, r5); H.w[3] = PERM_HI(r6, r7);
    L.w[0] = PERM_LO(r0, r1); L.w[1] = PERM_LO(r2, r3);
    L.w[2] = PERM_LO(r4, r5); L.w[3] = PERM_LO(r6, r7);
    h8 = H.v; l8 = L.v;
}

__global__ __launch_bounds__(256) void repack_kernel(
    const float* __restrict__ w1, const float* __restrict__ w2, const float* __restrict__ w3,
    const float* __restrict__ Wq, const float* __restrict__ Wk, const float* __restrict__ Wv,
    const float* __restrict__ Wfc, const float* __restrict__ Wout,
    const float* __restrict__ bfc, const float* __restrict__ bout,
    float* __restrict__ ws)
{
    int tid = blockIdx.x * 256 + threadIdx.x;
    unsigned int* wsu = (unsigned int*)ws;
    if (tid < 1024) {                        // conv1 dup-B: k-tap = ph*16 + lg*4 + r
        int r = tid & 3, lane = (tid >> 2) & 63, pat = (tid >> 8) & 1, ph = (tid >> 9) & 1;
        int li = lane & 15, lg = lane >> 4;
        int k = ph * 16 + lg * 4 + r;
        float f = (k < 26) ? w1[li * 26 + k] : 0.f;
        wsu[OFF_W1F + tid] = dup_word(f, pat);
    }
    int t2 = tid - 1024;
    if (t2 >= 0 && t2 < 13312) {             // conv2 32x32x16: step s = tap, slot = ci
        int r = t2 & 3, lane = (t2 >> 2) & 63, hl = (t2 >> 8) & 1, s = t2 >> 9;  // s 0..25
        int co = lane & 31;
        int ci0 = (lane >> 5) * 8;
        float f0 = w2[co * 416 + (ci0 + 2 * r) * 26 + s];
        float f1 = w2[co * 416 + (ci0 + 2 * r + 1) * 26 + s];
        wsu[OFF_W2F + t2] = frag_word(f0, f1, hl);
    }
    int t3 = tid - 14336;
    if (t3 >= 0 && t3 < 51200) {             // conv3 B-frags: k=j=q*32+ci
        int r = t3 & 3, l = (t3 >> 2) & 63, hl = (t3 >> 8) & 1;
        int nt = (t3 >> 9) & 3, s = t3 >> 11;
        int co = nt * 16 + (l & 15);
        int k0 = s * 32 + (l >> 4) * 8 + 2 * r;
        float f0 = w3[co * 800 + (k0 & 31) * 25 + (k0 >> 5)];
        float f1 = w3[co * 800 + ((k0 + 1) & 31) * 25 + ((k0 + 1) >> 5)];
        wsu[OFF_W3F + t3] = frag_word(f0, f1, hl);
    }
    int t4 = tid - 65536;
    if (t4 >= 0 && t4 < 98304) {             // Wqkv B-frags
        int r = t4 & 3, l = (t4 >> 2) & 63, hl = (t4 >> 8) & 1;
        int rest = t4 >> 9;
        int nt = rest % 12, rest2 = rest / 12;
        int ks = rest2 & 1, h = rest2 >> 1;
        int n = nt * 16 + (l & 15);
        int mat = n >> 6, e = n & 63;
        int d0 = ks * 32 + (l >> 4) * 8 + 2 * r;
        const float* W = (mat == 0) ? Wq : (mat == 1) ? Wk : Wv;
        float f0 = W[h * 4096 + e * 64 + d0];
        float f1 = W[h * 4096 + e * 64 + d0 + 1];
        wsu[OFF_WQKVF + t4] = frag_word(f0, f1, hl);
    }
    int t7 = tid - 163840;
    if (t7 >= 0 && t7 < 32768) {             // Wcomb[j][k]
        int k = t7 & 63, j = t7 >> 6;
        float acc = 0.f;
        #pragma unroll 8
        for (int d = 0; d < 64; ++d)
            acc = fmaf(Wfc[d * 512 + j], Wout[k * 64 + d], acc);
        ws[OFF_WCOMB + t7] = acc;
    }
    int t8 = tid - 196608;
    if (t8 >= 0 && t8 < 64) {                // cbias[k]
        float acc = bout[t8];
        #pragma unroll 8
        for (int d = 0; d < 64; ++d)
            acc = fmaf(bfc[d], Wout[t8 * 64 + d], acc);
        ws[OFF_CBIAS + t8] = acc;
    }
}

// One block = one 5-chunk tile. y1/y2 stored as separate hi/lo bf16 planes:
// conv2 A-frag = 2 ds_read_b64 per plane (zero perms); conv3 A-frag = 1
// ds_read_b128 per plane. conv2 staging: load -> MFMA -> ds_write (latency
// hidden). conv3 B-stream batched 5 steps deep.
__global__ __launch_bounds__(256, 4) void encoder_kernel(
    const float* __restrict__ audio1, const float* __restrict__ audio2,
    const float* __restrict__ b1, const float* __restrict__ g1, const float* __restrict__ be1,
    const float* __restrict__ m1, const float* __restrict__ v1,
    const float* __restrict__ b2, const float* __restrict__ g2, const float* __restrict__ be2,
    const float* __restrict__ m2, const float* __restrict__ v2,
    const float* __restrict__ b3, const float* __restrict__ g3, const float* __restrict__ be3,
    const float* __restrict__ m3, const float* __restrict__ v3,
    float* __restrict__ ws, int B)
{
    __shared__ __align__(16) unsigned int smem[9584];
    unsigned int* a_p = smem;                              // 192
    unsigned int* w2f = smem + 192;                        // 2 x 1024 dbuf
    unsigned short* y1h16 = (unsigned short*)(smem + 2240);// 154 rows x 20 u16 (16 used)
    unsigned short* y1l16 = (unsigned short*)(smem + 3780);
    unsigned short* y2h16 = (unsigned short*)(smem + 5320);// 5 x 808 u16 (800 used)
    unsigned short* y2l16 = (unsigned short*)(smem + 7340);
    float* A_s  = (float*)(smem + 9360);                   // 112
    float* Bc_s = (float*)(smem + 9472);                   // 112

    int t = threadIdx.x;
    int blk = blockIdx.x;
    int seq = blk / 5, tile = blk - seq * 5;
    int tc = (tile == 4) ? 2 : 5;
    int nq = 25 * tc;                        // 125 or 50
    int ny1 = nq + 25;
    int na = nq + 50;
    const unsigned int* wsu = (const unsigned int*)ws;
    int lane = t & 63, wid = t >> 6;
    int li = lane & 15, lg = lane >> 4;

    const float* audio = (seq < B ? audio1 + (size_t)seq * SEQLEN
                                  : audio2 + (size_t)(seq - B) * SEQLEN) + tile * 125;
    // conv1 B-frags direct from L2 into regs (w1f LDS dropped)
    uint4 w1b[2][2];
    #pragma unroll
    for (int ph = 0; ph < 2; ++ph)
        #pragma unroll
        for (int pat = 0; pat < 2; ++pat)
            w1b[ph][pat] = *(const uint4*)(wsu + OFF_W1F + ((ph * 2 + pat) * 64 + lane) * 4);

    if (t < 192) a_p[t] = (t < na) ? pack_hl(audio[t]) : 0u;
    *(uint4*)(w2f + t * 4) = *(const uint4*)(wsu + OFF_W2F + t * 4);   // stage 0 (taps 0,1)
    if (t < 16)       { float A = g1[t] * rsqrtf(v1[t] + BN_EPS); A_s[t] = A; Bc_s[t] = (b1[t] - m1[t]) * A + be1[t]; }
    else if (t < 48)  { int i = t - 16; float A = g2[i] * rsqrtf(v2[i] + BN_EPS); A_s[t] = A; Bc_s[t] = (b2[i] - m2[i]) * A + be2[i]; }
    else if (t < 112) { int i = t - 48; float A = g3[i] * rsqrtf(v3[i] + BN_EPS); A_s[t] = A; Bc_s[t] = (b3[i] - m3[i]) * A + be3[i]; }
    // zero y1 tail rows (p >= ny1), u32 view
    for (int i = ny1 * 10 + t; i < 1540; i += 256) {
        (smem + 2240)[i] = 0u;
        (smem + 3780)[i] = 0u;
    }
    __syncthreads();

    // ---- conv1 MFMA (dup-B): D[p][ci], Mtiles strided over waves ----
    {
        int nMt1 = (ny1 + 15) >> 4;
        float Ai = A_s[li], Bi = Bc_s[li];
        for (int mt = wid; mt < nMt1; mt += 4) {
            f32x4 acc = {0.f, 0.f, 0.f, 0.f};
            #pragma unroll
            for (int ph = 0; ph < 2; ++ph) {
                const unsigned int* ap = a_p + mt * 16 + li + ph * 16 + lg * 4;
                union { unsigned int w[4]; bf16x8 v; } A;
                A.w[0] = ap[0]; A.w[1] = ap[1]; A.w[2] = ap[2]; A.w[3] = ap[3];
                bf16x8 b0 = *(const bf16x8*)&w1b[ph][0];
                bf16x8 b1 = *(const bf16x8*)&w1b[ph][1];
                acc = __builtin_amdgcn_mfma_f32_16x16x32_bf16(A.v, b0, acc, 0, 0, 0);
                acc = __builtin_amdgcn_mfma_f32_16x16x32_bf16(A.v, b1, acc, 0, 0, 0);
            }
            #pragma unroll
            for (int r = 0; r < 4; ++r) {
                int p = mt * 16 + lg * 4 + r;
                if (p < ny1) {
                    float f = swishf(fmaf(acc[r], Ai, Bi));
                    unsigned short hh = bf16_rne(f);
                    unsigned short ll = bf16_rne(f - bf16_tof(hh));
                    y1h16[p * 20 + li] = hh;
                    y1l16[p * 20 + li] = ll;
                }
            }
        }
    }
    __syncthreads();

    // ---- conv2 MFMA 32x32x16: 13 stages x 2 taps, two-plane A (zero perms) ----
    int row0 = wid * 32 + (lane & 31);       // output position q
    int ci0 = (lane >> 5) * 8;
    f32x16 acc2;
    #pragma unroll
    for (int r = 0; r < 16; ++r) acc2[r] = 0.f;

    for (int stg = 0; stg < 13; ++stg) {
        uint4 vnext;
        if (stg < 12)
            vnext = *(const uint4*)(wsu + OFF_W2F + (stg + 1) * 1024 + t * 4);
        const unsigned int* cur = w2f + (stg & 1) * 1024;
        #pragma unroll
        for (int half = 0; half < 2; ++half) {
            int s = stg * 2 + half;
            bf16x8 bh = *(const bf16x8*)(cur + half * 512 + lane * 4);
            bf16x8 bl = *(const bf16x8*)(cur + half * 512 + 256 + lane * 4);
            const unsigned short* hp = y1h16 + (row0 + s) * 20 + ci0;
            const unsigned short* lp = y1l16 + (row0 + s) * 20 + ci0;
            union { uint2 u[2]; bf16x8 v; } Ah, Al;
            Ah.u[0] = *(const uint2*)hp; Ah.u[1] = *(const uint2*)(hp + 4);
            Al.u[0] = *(const uint2*)lp; Al.u[1] = *(const uint2*)(lp + 4);
            acc2 = __builtin_amdgcn_mfma_f32_32x32x16_bf16(Ah.v, bh, acc2, 0, 0, 0);
            acc2 = __builtin_amdgcn_mfma_f32_32x32x16_bf16(Al.v, bh, acc2, 0, 0, 0);
            acc2 = __builtin_amdgcn_mfma_f32_32x32x16_bf16(Ah.v, bl, acc2, 0, 0, 0);
        }
        if (stg < 12)
            *(uint4*)(w2f + ((stg + 1) & 1) * 1024 + t * 4) = vnext;
        __syncthreads();
    }
    // epilogue: bn + swish -> y2 planes [cc][q'*32 + co]
    {
        int co = lane & 31;
        float Ac = A_s[16 + co], Bc = Bc_s[16 + co];
        int rbase = 4 * (lane >> 5) + wid * 32;
        #pragma unroll
        for (int reg = 0; reg < 16; ++reg) {
            int q = rbase + (reg & 3) + 8 * (reg >> 2);
            if (q < nq) {
                int cc = q / 25, qp = q - cc * 25;
                float f = swishf(fmaf(acc2[reg], Ac, Bc));
                unsigned short hh = bf16_rne(f);
                unsigned short ll = bf16_rne(f - bf16_tof(hh));
                y2h16[cc * 808 + qp * 32 + co] = hh;
                y2l16[cc * 808 + qp * 32 + co] = ll;
            }
        }
    }
    __syncthreads();

    // ---- conv3 MFMA 16x16x32: wave = Ntile, 25 steps in batches of 5 ----
    {
        const uint4* w3f4 = (const uint4*)(wsu + OFF_W3F);
        f32x4 acc3 = {0.f, 0.f, 0.f, 0.f};
        for (int b5 = 0; b5 < 5; ++b5) {
            uint4 BH[5], BL[5];
            #pragma unroll
            for (int i = 0; i < 5; ++i) {
                int s = b5 * 5 + i;
                BH[i] = w3f4[((s * 4 + wid) * 2 + 0) * 64 + lane];
                BL[i] = w3f4[((s * 4 + wid) * 2 + 1) * 64 + lane];
            }
            #pragma unroll
            for (int i = 0; i < 5; ++i) {
                int s = b5 * 5 + i;
                bf16x8 ah = {}, al = {};
                if (li < tc) {
                    ah = *(const bf16x8*)(y2h16 + li * 808 + s * 32 + lg * 8);
                    al = *(const bf16x8*)(y2l16 + li * 808 + s * 32 + lg * 8);
                }
                bf16x8 bh = *(const bf16x8*)&BH[i];
                bf16x8 bl = *(const bf16x8*)&BL[i];
                acc3 = __builtin_amdgcn_mfma_f32_16x16x32_bf16(ah, bh, acc3, 0, 0, 0);
                acc3 = __builtin_amdgcn_mfma_f32_16x16x32_bf16(al, bh, acc3, 0, 0, 0);
                acc3 = __builtin_amdgcn_mfma_f32_16x16x32_bf16(ah, bl, acc3, 0, 0, 0);
            }
        }
        int co = wid * 16 + li;
        float A3 = A_s[48 + co], B3 = Bc_s[48 + co];
        unsigned int* featp = (unsigned int*)ws + OFF_FEAT;
        #pragma unroll
        for (int r = 0; r < 4; ++r) {
            int cc = lg * 4 + r;
            if (cc < tc)
                featp[((size_t)(seq * NCHUNK + tile * 5 + cc)) * 64 + co]
                    = pack_hl(swishf(fmaf(acc3[r], A3, B3)));
        }
    }
}

// One block per sequence. QKV MFMA with 1-deep cross-iteration B-frag prefetch;
// 3 barriers/head (softmax+colmean+AV on wave 0); fc+Wout folded into Wcomb.
__global__ __launch_bounds__(256, 4) void mha_kernel(
    const float* __restrict__ ws,
    const float* __restrict__ bq, const float* __restrict__ bk, const float* __restrict__ bv,
    float* __restrict__ out, int B)
{
    __shared__ float smem[7696];
    unsigned int* f_p = (unsigned int*)smem;  // 32 x 68 packed (rows 22..31 zero)
    float* q_s    = smem + 2176;  // 22 x 64
    float* k_s    = smem + 3584;  // 22 x 65
    float* v_s    = smem + 5014;  // 22 x 64
    float* s_s    = smem + 6422;  // 22 x 22
    float* abar_s = smem + 6906;  // 22
    float* obar_s = smem + 6928;  // 8 x 64
    float* fred   = smem + 7440;  // 4 x 64

    int t = threadIdx.x, b = blockIdx.x;
    int lane = t & 63, wid = t >> 6;
    int li = lane & 15, lg = lane >> 4;
    const unsigned int* featp = (const unsigned int*)ws + OFF_FEAT + (size_t)b * 1408;
    for (int i = t; i < 1408; i += 256) f_p[(i >> 6) * 68 + (i & 63)] = featp[i];
    for (int i = 1496 + t; i < 2176; i += 256) f_p[i] = 0u;
    __syncthreads();

    bf16x8 fah[2][2], fal[2][2];
    #pragma unroll
    for (int mt = 0; mt < 2; ++mt)
        #pragma unroll
        for (int ks = 0; ks < 2; ++ks)
            frag_from_packed(f_p + (mt * 16 + li) * 68 + ks * 32 + lg * 8,
                             fah[mt][ks], fal[mt][ks]);

    const uint4* wqkvf4 = (const uint4*)((const unsigned int*)ws + OFF_WQKVF);
    // preload (h=0, j=0)
    uint4 nb00, nb01, nb10, nb11;
    {
        int nt = wid * 3;
        nb00 = wqkvf4[(((0 * 2 + 0) * 12 + nt) * 2 + 0) * 64 + lane];
        nb01 = wqkvf4[(((0 * 2 + 0) * 12 + nt) * 2 + 1) * 64 + lane];
        nb10 = wqkvf4[(((0 * 2 + 1) * 12 + nt) * 2 + 0) * 64 + lane];
        nb11 = wqkvf4[(((0 * 2 + 1) * 12 + nt) * 2 + 1) * 64 + lane];
    }

    for (int h = 0; h < 8; ++h) {
        #pragma unroll
        for (int j = 0; j < 3; ++j) {
            uint4 c00 = nb00, c01 = nb01, c10 = nb10, c11 = nb11;
            int hj = h * 3 + j;
            if (hj < 23) {
                int hn = (hj + 1) / 3, jn = (hj + 1) - hn * 3;
                int ntn = wid * 3 + jn;
                nb00 = wqkvf4[(((hn * 2 + 0) * 12 + ntn) * 2 + 0) * 64 + lane];
                nb01 = wqkvf4[(((hn * 2 + 0) * 12 + ntn) * 2 + 1) * 64 + lane];
                nb10 = wqkvf4[(((hn * 2 + 1) * 12 + ntn) * 2 + 0) * 64 + lane];
                nb11 = wqkvf4[(((hn * 2 + 1) * 12 + ntn) * 2 + 1) * 64 + lane];
            }
            int nt = wid * 3 + j;
            f32x4 a0 = {0.f, 0.f, 0.f, 0.f}, a1 = a0;
            {
                bf16x8 bh = *(const bf16x8*)&c00, bl = *(const bf16x8*)&c01;
                a0 = __builtin_amdgcn_mfma_f32_16x16x32_bf16(fah[0][0], bh, a0, 0, 0, 0);
                a0 = __builtin_amdgcn_mfma_f32_16x16x32_bf16(fal[0][0], bh, a0, 0, 0, 0);
                a0 = __builtin_amdgcn_mfma_f32_16x16x32_bf16(fah[0][0], bl, a0, 0, 0, 0);
                a1 = __builtin_amdgcn_mfma_f32_16x16x32_bf16(fah[1][0], bh, a1, 0, 0, 0);
                a1 = __builtin_amdgcn_mfma_f32_16x16x32_bf16(fal[1][0], bh, a1, 0, 0, 0);
                a1 = __builtin_amdgcn_mfma_f32_16x16x32_bf16(fah[1][0], bl, a1, 0, 0, 0);
            }
            {
                bf16x8 bh = *(const bf16x8*)&c10, bl = *(const bf16x8*)&c11;
                a0 = __builtin_amdgcn_mfma_f32_16x16x32_bf16(fah[0][1], bh, a0, 0, 0, 0);
                a0 = __builtin_amdgcn_mfma_f32_16x16x32_bf16(fal[0][1], bh, a0, 0, 0, 0);
                a0 = __builtin_amdgcn_mfma_f32_16x16x32_bf16(fah[0][1], bl, a0, 0, 0, 0);
                a1 = __builtin_amdgcn_mfma_f32_16x16x32_bf16(fah[1][1], bh, a1, 0, 0, 0);
                a1 = __builtin_amdgcn_mfma_f32_16x16x32_bf16(fal[1][1], bh, a1, 0, 0, 0);
                a1 = __builtin_amdgcn_mfma_f32_16x16x32_bf16(fah[1][1], bl, a1, 0, 0, 0);
            }
            int mat = nt >> 2;
            int e = (nt & 3) * 16 + li;
            float* dst; int stride; float bias;
            if (mat == 0)      { dst = q_s; stride = 64; bias = bq[h * 64 + e]; }
            else if (mat == 1) { dst = k_s; stride = 65; bias = bk[h * 64 + e]; }
            else               { dst = v_s; stride = 64; bias = bv[h * 64 + e]; }
            #pragma unroll
            for (int r = 0; r < 4; ++r) {
                int row0 = lg * 4 + r;
                dst[row0 * stride + e] = a0[r] + bias;
                int row1 = 16 + row0;
                if (row1 < 22) dst[row1 * stride + e] = a1[r] + bias;
            }
        }
        __syncthreads();
        // scores S = Q K^T (all waves)
        for (int o = t; o < 484; o += 256) {
            int s = o / 22, u = o - s * 22;
            float acc = 0.f;
            #pragma unroll 16
            for (int d = 0; d < 64; ++d) acc = fmaf(q_s[s * 64 + d], k_s[u * 65 + d], acc);
            s_s[s * 22 + u] = acc;
        }
        __syncthreads();
        // wave 0: softmax + column-mean + pooled AV (wave-internal ordering)
        if (t < 64) {
            if (t < 22) {
                float m = -1e30f;
                #pragma unroll
                for (int j2 = 0; j2 < 22; ++j2) m = fmaxf(m, s_s[t * 22 + j2]);
                float sum = 0.f;
                #pragma unroll
                for (int j2 = 0; j2 < 22; ++j2) { float ev = __expf(s_s[t * 22 + j2] - m); s_s[t * 22 + j2] = ev; sum += ev; }
                float rr = 1.f / sum;
                #pragma unroll
                for (int j2 = 0; j2 < 22; ++j2) s_s[t * 22 + j2] *= rr;
            }
            if (t < 22) {
                float a = 0.f;
                #pragma unroll
                for (int s = 0; s < 22; ++s) a += s_s[s * 22 + t];
                abar_s[t] = a * (1.f / 22.f);
            }
            float acc = 0.f;
            #pragma unroll
            for (int u = 0; u < 22; ++u) acc = fmaf(abar_s[u], v_s[u * 64 + t], acc);
            obar_s[h * 64 + t] = acc;
        }
        __syncthreads();
    }
    // out = cbias + obar(512) @ Wcomb, split over 4 waves
    {
        int d = t & 63, part = t >> 6;
        const float* wcomb = ws + OFF_WCOMB;
        float acc = 0.f;
        for (int j = part * 128; j < part * 128 + 128; ++j)
            acc = fmaf(obar_s[j], wcomb[j * 64 + d], acc);
        fred[part * 64 + d] = acc;
    }
    __syncthreads();
    if (t < 64) {
        const float* cbias = ws + OFF_CBIAS;
        out[(size_t)b * 64 + t] = cbias[t] + fred[t] + fred[64 + t] + fred[128 + t] + fred[192 + t];
    }
}

extern "C" void kernel_launch(void* const* d_in, const int* in_sizes, int n_in,
                              void* d_out, int out_size, void* d_ws, size_t ws_size,
                              hipStream_t stream) {
    const float* audio1 = (const float*)d_in[0];
    const float* audio2 = (const float*)d_in[1];
    const float* w1   = (const float*)d_in[2];
    const float* b1   = (const float*)d_in[3];
    const float* g1   = (const float*)d_in[4];
    const float* be1  = (const float*)d_in[5];
    const float* m1   = (const float*)d_in[6];
    const float* v1   = (const float*)d_in[7];
    const float* w2   = (const float*)d_in[8];
    const float* b2   = (const float*)d_in[9];
    const float* g2   = (const float*)d_in[10];
    const float* be2  = (const float*)d_in[11];
    const float* m2   = (const float*)d_in[12];
    const float* v2   = (const float*)d_in[13];
    const float* w3   = (const float*)d_in[14];
    const float* b3   = (const float*)d_in[15];
    const float* g3   = (const float*)d_in[16];
    const float* be3  = (const float*)d_in[17];
    const float* m3   = (const float*)d_in[18];
    const float* v3   = (const float*)d_in[19];
    const float* Wq   = (const float*)d_in[20];
    const float* bq   = (const float*)d_in[21];
    const float* Wk   = (const float*)d_in[22];
    const float* bk   = (const float*)d_in[23];
    const float* Wv   = (const float*)d_in[24];
    const float* bv   = (const float*)d_in[25];
    const float* Wfc  = (const float*)d_in[26];
    const float* bfc  = (const float*)d_in[27];
    const float* Wout = (const float*)d_in[28];
    const float* bout = (const float*)d_in[29];

    float* ws  = (float*)d_ws;
    float* out = (float*)d_out;
    int B = in_sizes[0] / SEQLEN;   // 4096
    int nseq = 2 * B;

    repack_kernel<<<(REPACK_N + 255) / 256, 256, 0, stream>>>(
        w1, w2, w3, Wq, Wk, Wv, Wfc, Wout, bfc, bout, ws);
    encoder_kernel<<<nseq * 5, 256, 0, stream>>>(audio1, audio2,
        b1, g1, be1, m1, v1,
        b2, g2, be2, m2, v2,
        b3, g3, be3, m3, v3,
        ws, B);
    mha_kernel<<<nseq, 256, 0, stream>>>(ws, bq, bk, bv, out, B);
}

// Round 8
// 1128.525 us; speedup vs baseline: 1.3541x; 1.0615x over previous
//
#include <hip/hip_runtime.h>
#include <math.h>

#define NCHUNK 22
#define SEQLEN 600
#define BN_EPS 1e-5f

// ws offsets (4-byte units)
#define OFF_W1F    0         // 1024   u32 : conv1 B dup-frags [ph2][pat2][lane][r]
#define OFF_W2F    1024      // 13312  u32 : conv2 32x32 B-frags [s26][hl2][lane][r4]
#define OFF_W3F    14336     // 51200  u32 : conv3 B-frags [s25][nt4][hl2][lane][r4]
#define OFF_MHF    65536     // 32768  u32 : Mh=WqT*Wk B-frags [h8][ks2][nt4][hl2][lane][r4]
#define OFF_WC     98304     // 32768  f32 : WC[j=h*64+d][k] = Wv-folded (Wfc.Wout)
#define OFF_UH     131072    // 512    f32 : u_h[h][d] = sum_e Wq[h,e,d]*bk[h,e]
#define OFF_WH     131584    // 512    f32 : w_h[h][d] = sum_e Wk[h,e,d]*bq[h,e]
#define OFF_CH     132096    // 8      f32 : c_h = bq.bk
#define OFF_CBIAS  132104    // 64     f32 : all-bias fold (cbias kernel)
#define OFF_FEAT   132168    // 2*B*22*64 u32 (PACKED hi|lo)
#define REPACK_N   132104

typedef short bf16x8 __attribute__((ext_vector_type(8)));
typedef float f32x4 __attribute__((ext_vector_type(4)));
typedef float f32x16 __attribute__((ext_vector_type(16)));

#if __has_builtin(__builtin_amdgcn_perm)
#define PERM_HI(r0, r1) __builtin_amdgcn_perm((r1), (r0), 0x05040100u)
#define PERM_LO(r0, r1) __builtin_amdgcn_perm((r1), (r0), 0x07060302u)
#else
#define PERM_HI(r0, r1) (((r0) & 0xFFFFu) | ((r1) << 16))
#define PERM_LO(r0, r1) (((r0) >> 16) | ((r1) & 0xFFFF0000u))
#endif

__device__ __forceinline__ float swishf(float z) {
    return z / (1.f + __expf(-z));
}
__device__ __forceinline__ unsigned short bf16_rne(float f) {
    unsigned int u = __float_as_uint(f);
    return (unsigned short)((u + 0x7FFFu + ((u >> 16) & 1u)) >> 16);
}
__device__ __forceinline__ float bf16_tof(unsigned short h) {
    return __uint_as_float(((unsigned int)h) << 16);
}
// packed u32: low16 = hi-bf16, high16 = lo-bf16 (residual)
__device__ __forceinline__ unsigned int pack_hl(float f) {
    unsigned int u = __float_as_uint(f);
    unsigned int h = (u + 0x7FFFu + ((u >> 16) & 1u)) >> 16;
    float r = f - __uint_as_float(h << 16);
    unsigned int v = __float_as_uint(r);
    unsigned int l = (v + 0x7FFFu + ((v >> 16) & 1u)) >> 16;
    return h | (l << 16);
}
// dup-B word (conv1): both halves = bf16_hi(f) (pat=0) or bf16_lo(f) (pat=1)
__device__ __forceinline__ unsigned int dup_word(float f, int pat) {
    unsigned short h = bf16_rne(f);
    unsigned short v = pat ? bf16_rne(f - bf16_tof(h)) : h;
    return (unsigned int)v | ((unsigned int)v << 16);
}
// split B word: (bf16 part of f0, bf16 part of f1)
__device__ __forceinline__ unsigned int frag_word(float f0, float f1, int hl) {
    unsigned short h0 = bf16_rne(f0), h1 = bf16_rne(f1);
    if (hl == 0) return (unsigned int)h0 | ((unsigned int)h1 << 16);
    unsigned short l0 = bf16_rne(f0 - bf16_tof(h0));
    unsigned short l1 = bf16_rne(f1 - bf16_tof(h1));
    return (unsigned int)l0 | ((unsigned int)l1 << 16);
}
// hi/lo bf16x8 A-fragments from 8 packed u32 (contiguous)
__device__ __forceinline__ void frag_from_packed(const unsigned int* p, bf16x8& h8, bf16x8& l8) {
    unsigned int r0 = p[0], r1 = p[1], r2 = p[2], r3 = p[3];
    unsigned int r4 = p[4], r5 = p[5], r6 = p[6], r7 = p[7];
    union U { unsigned int w[4]; bf16x8 v; } H, L;
    H.w[0] = PERM_HI(r0, r1); H.w[1] = PERM_HI(r2, r3);
    H.w[2] = PERM_HI(r4, r5); H.w[3] = PERM_HI(r6, r7);
    L.w[0] = PERM_LO(r0, r1); L.w[1] = PERM_LO(r2, r3);
    L.w[2] = PERM_LO(r4, r5); L.w[3] = PERM_LO(r6, r7);
    h8 = H.v; l8 = L.v;
}

__global__ __launch_bounds__(256) void repack_kernel(
    const float* __restrict__ w1, const float* __restrict__ w2, const float* __restrict__ w3,
    const float* __restrict__ Wq, const float* __restrict__ Wk, const float* __restrict__ Wv,
    const float* __restrict__ Wfc, const float* __restrict__ Wout,
    const float* __restrict__ bq, const float* __restrict__ bk,
    float* __restrict__ ws)
{
    int tid = blockIdx.x * 256 + threadIdx.x;
    unsigned int* wsu = (unsigned int*)ws;
    if (tid < 1024) {                        // conv1 dup-B: k-tap = ph*16 + lg*4 + r
        int r = tid & 3, lane = (tid >> 2) & 63, pat = (tid >> 8) & 1, ph = (tid >> 9) & 1;
        int li = lane & 15, lg = lane >> 4;
        int k = ph * 16 + lg * 4 + r;
        float f = (k < 26) ? w1[li * 26 + k] : 0.f;
        wsu[OFF_W1F + tid] = dup_word(f, pat);
    }
    int t2 = tid - 1024;
    if (t2 >= 0 && t2 < 13312) {             // conv2 32x32x16: step s = tap, slot = ci
        int r = t2 & 3, lane = (t2 >> 2) & 63, hl = (t2 >> 8) & 1, s = t2 >> 9;  // s 0..25
        int co = lane & 31;
        int ci0 = (lane >> 5) * 8;
        float f0 = w2[co * 416 + (ci0 + 2 * r) * 26 + s];
        float f1 = w2[co * 416 + (ci0 + 2 * r + 1) * 26 + s];
        wsu[OFF_W2F + t2] = frag_word(f0, f1, hl);
    }
    int t3 = tid - 14336;
    if (t3 >= 0 && t3 < 51200) {             // conv3 B-frags: k=j=q*32+ci
        int r = t3 & 3, l = (t3 >> 2) & 63, hl = (t3 >> 8) & 1;
        int nt = (t3 >> 9) & 3, s = t3 >> 11;
        int co = nt * 16 + (l & 15);
        int k0 = s * 32 + (l >> 4) * 8 + 2 * r;
        float f0 = w3[co * 800 + (k0 & 31) * 25 + (k0 >> 5)];
        float f1 = w3[co * 800 + ((k0 + 1) & 31) * 25 + ((k0 + 1) >> 5)];
        wsu[OFF_W3F + t3] = frag_word(f0, f1, hl);
    }
    int t4 = tid - 65536;
    if (t4 >= 0 && t4 < 32768) {             // Mh B-frags: B[k=d][col=d'], Mh=WqT.Wk
        int r = t4 & 3, l = (t4 >> 2) & 63, hl = (t4 >> 8) & 1;
        int nt = (t4 >> 9) & 3, ks = (t4 >> 11) & 1, h = t4 >> 12;
        int n = nt * 16 + (l & 15);
        int d0 = ks * 32 + (l >> 4) * 8 + 2 * r;
        const float* wqh = Wq + h * 4096;
        const float* wkh = Wk + h * 4096;
        float f0 = 0.f, f1 = 0.f;
        #pragma unroll 8
        for (int e = 0; e < 64; ++e) {
            float wk_en = wkh[e * 64 + n];
            f0 = fmaf(wqh[e * 64 + d0],     wk_en, f0);
            f1 = fmaf(wqh[e * 64 + d0 + 1], wk_en, f1);
        }
        wsu[OFF_MHF + t4] = frag_word(f0, f1, hl);
    }
    int t7 = tid - 98304;
    if (t7 >= 0 && t7 < 32768) {             // WC[j=h*64+d][k]
        int k = t7 & 63;
        int j = __builtin_amdgcn_readfirstlane(t7 >> 6);  // wave-uniform
        int h = j >> 6, d = j & 63;
        float acc = 0.f;
        for (int e = 0; e < 64; ++e) {
            const float* wfc_col = Wfc + h * 64 + e;       // Wfc[dp][h*64+e]
            float inner = 0.f;
            #pragma unroll 8
            for (int dp = 0; dp < 64; ++dp)
                inner = fmaf(wfc_col[dp * 512], Wout[k * 64 + dp], inner);
            acc = fmaf(Wv[h * 4096 + e * 64 + d], inner, acc);
        }
        ws[OFF_WC + t7] = acc;
    }
    int t8 = tid - 131072;
    if (t8 >= 0 && t8 < 512) {               // u_h[h][d]
        int h = t8 >> 6, d = t8 & 63;
        float acc = 0.f;
        #pragma unroll 8
        for (int e = 0; e < 64; ++e) acc = fmaf(Wq[h * 4096 + e * 64 + d], bk[h * 64 + e], acc);
        ws[OFF_UH + t8] = acc;
    }
    int t9 = tid - 131584;
    if (t9 >= 0 && t9 < 512) {               // w_h[h][d]
        int h = t9 >> 6, d = t9 & 63;
        float acc = 0.f;
        #pragma unroll 8
        for (int e = 0; e < 64; ++e) acc = fmaf(Wk[h * 4096 + e * 64 + d], bq[h * 64 + e], acc);
        ws[OFF_WH + t9] = acc;
    }
    int t10 = tid - 132096;
    if (t10 >= 0 && t10 < 8) {               // c_h
        float acc = 0.f;
        #pragma unroll 8
        for (int e = 0; e < 64; ++e) acc = fmaf(bq[t10 * 64 + e], bk[t10 * 64 + e], acc);
        ws[OFF_CH + t10] = acc;
    }
}

// cbias'[k] = bout[k] + sum_dp (bfc[dp] + sum_j bv[j]*Wfc[dp][j]) * Wout[k][dp]
__global__ __launch_bounds__(64) void cbias_kernel(
    const float* __restrict__ Wfc, const float* __restrict__ Wout,
    const float* __restrict__ bfc, const float* __restrict__ bout,
    const float* __restrict__ bv, float* __restrict__ ws)
{
    __shared__ float sd_s[64];
    int t = threadIdx.x;
    float acc = 0.f;
    for (int j = 0; j < 512; ++j) acc = fmaf(bv[j], Wfc[t * 512 + j], acc);
    sd_s[t] = acc;
    __syncthreads();
    float cb = bout[t];
    #pragma unroll 8
    for (int dp = 0; dp < 64; ++dp) cb = fmaf(bfc[dp] + sd_s[dp], Wout[t * 64 + dp], cb);
    ws[OFF_CBIAS + t] = cb;
}

// ---- encoder: unchanged from R7 (proven) except OFF_FEAT value ----
__global__ __launch_bounds__(256, 4) void encoder_kernel(
    const float* __restrict__ audio1, const float* __restrict__ audio2,
    const float* __restrict__ b1, const float* __restrict__ g1, const float* __restrict__ be1,
    const float* __restrict__ m1, const float* __restrict__ v1,
    const float* __restrict__ b2, const float* __restrict__ g2, const float* __restrict__ be2,
    const float* __restrict__ m2, const float* __restrict__ v2,
    const float* __restrict__ b3, const float* __restrict__ g3, const float* __restrict__ be3,
    const float* __restrict__ m3, const float* __restrict__ v3,
    float* __restrict__ ws, int B)
{
    __shared__ __align__(16) unsigned int smem[9584];
    unsigned int* a_p = smem;                              // 192
    unsigned int* w2f = smem + 192;                        // 2 x 1024 dbuf
    unsigned short* y1h16 = (unsigned short*)(smem + 2240);// 154 rows x 20 u16 (16 used)
    unsigned short* y1l16 = (unsigned short*)(smem + 3780);
    unsigned short* y2h16 = (unsigned short*)(smem + 5320);// 5 x 808 u16 (800 used)
    unsigned short* y2l16 = (unsigned short*)(smem + 7340);
    float* A_s  = (float*)(smem + 9360);                   // 112
    float* Bc_s = (float*)(smem + 9472);                   // 112

    int t = threadIdx.x;
    int blk = blockIdx.x;
    int seq = blk / 5, tile = blk - seq * 5;
    int tc = (tile == 4) ? 2 : 5;
    int nq = 25 * tc;                        // 125 or 50
    int ny1 = nq + 25;
    int na = nq + 50;
    const unsigned int* wsu = (const unsigned int*)ws;
    int lane = t & 63, wid = t >> 6;
    int li = lane & 15, lg = lane >> 4;

    const float* audio = (seq < B ? audio1 + (size_t)seq * SEQLEN
                                  : audio2 + (size_t)(seq - B) * SEQLEN) + tile * 125;
    uint4 w1b[2][2];
    #pragma unroll
    for (int ph = 0; ph < 2; ++ph)
        #pragma unroll
        for (int pat = 0; pat < 2; ++pat)
            w1b[ph][pat] = *(const uint4*)(wsu + OFF_W1F + ((ph * 2 + pat) * 64 + lane) * 4);

    if (t < 192) a_p[t] = (t < na) ? pack_hl(audio[t]) : 0u;
    *(uint4*)(w2f + t * 4) = *(const uint4*)(wsu + OFF_W2F + t * 4);   // stage 0 (taps 0,1)
    if (t < 16)       { float A = g1[t] * rsqrtf(v1[t] + BN_EPS); A_s[t] = A; Bc_s[t] = (b1[t] - m1[t]) * A + be1[t]; }
    else if (t < 48)  { int i = t - 16; float A = g2[i] * rsqrtf(v2[i] + BN_EPS); A_s[t] = A; Bc_s[t] = (b2[i] - m2[i]) * A + be2[i]; }
    else if (t < 112) { int i = t - 48; float A = g3[i] * rsqrtf(v3[i] + BN_EPS); A_s[t] = A; Bc_s[t] = (b3[i] - m3[i]) * A + be3[i]; }
    for (int i = ny1 * 10 + t; i < 1540; i += 256) {
        (smem + 2240)[i] = 0u;
        (smem + 3780)[i] = 0u;
    }
    __syncthreads();

    // conv1 MFMA (dup-B)
    {
        int nMt1 = (ny1 + 15) >> 4;
        float Ai = A_s[li], Bi = Bc_s[li];
        for (int mt = wid; mt < nMt1; mt += 4) {
            f32x4 acc = {0.f, 0.f, 0.f, 0.f};
            #pragma unroll
            for (int ph = 0; ph < 2; ++ph) {
                const unsigned int* ap = a_p + mt * 16 + li + ph * 16 + lg * 4;
                union { unsigned int w[4]; bf16x8 v; } A;
                A.w[0] = ap[0]; A.w[1] = ap[1]; A.w[2] = ap[2]; A.w[3] = ap[3];
                bf16x8 b0 = *(const bf16x8*)&w1b[ph][0];
                bf16x8 b1 = *(const bf16x8*)&w1b[ph][1];
                acc = __builtin_amdgcn_mfma_f32_16x16x32_bf16(A.v, b0, acc, 0, 0, 0);
                acc = __builtin_amdgcn_mfma_f32_16x16x32_bf16(A.v, b1, acc, 0, 0, 0);
            }
            #pragma unroll
            for (int r = 0; r < 4; ++r) {
                int p = mt * 16 + lg * 4 + r;
                if (p < ny1) {
                    float f = swishf(fmaf(acc[r], Ai, Bi));
                    unsigned short hh = bf16_rne(f);
                    unsigned short ll = bf16_rne(f - bf16_tof(hh));
                    y1h16[p * 20 + li] = hh;
                    y1l16[p * 20 + li] = ll;
                }
            }
        }
    }
    __syncthreads();

    // conv2 MFMA 32x32x16, two-plane A
    int row0 = wid * 32 + (lane & 31);
    int ci0 = (lane >> 5) * 8;
    f32x16 acc2;
    #pragma unroll
    for (int r = 0; r < 16; ++r) acc2[r] = 0.f;

    for (int stg = 0; stg < 13; ++stg) {
        uint4 vnext;
        if (stg < 12)
            vnext = *(const uint4*)(wsu + OFF_W2F + (stg + 1) * 1024 + t * 4);
        const unsigned int* cur = w2f + (stg & 1) * 1024;
        #pragma unroll
        for (int half = 0; half < 2; ++half) {
            int s = stg * 2 + half;
            bf16x8 bh = *(const bf16x8*)(cur + half * 512 + lane * 4);
            bf16x8 bl = *(const bf16x8*)(cur + half * 512 + 256 + lane * 4);
            const unsigned short* hp = y1h16 + (row0 + s) * 20 + ci0;
            const unsigned short* lp = y1l16 + (row0 + s) * 20 + ci0;
            union { uint2 u[2]; bf16x8 v; } Ah, Al;
            Ah.u[0] = *(const uint2*)hp; Ah.u[1] = *(const uint2*)(hp + 4);
            Al.u[0] = *(const uint2*)lp; Al.u[1] = *(const uint2*)(lp + 4);
            acc2 = __builtin_amdgcn_mfma_f32_32x32x16_bf16(Ah.v, bh, acc2, 0, 0, 0);
            acc2 = __builtin_amdgcn_mfma_f32_32x32x16_bf16(Al.v, bh, acc2, 0, 0, 0);
            acc2 = __builtin_amdgcn_mfma_f32_32x32x16_bf16(Ah.v, bl, acc2, 0, 0, 0);
        }
        if (stg < 12)
            *(uint4*)(w2f + ((stg + 1) & 1) * 1024 + t * 4) = vnext;
        __syncthreads();
    }
    {
        int co = lane & 31;
        float Ac = A_s[16 + co], Bc = Bc_s[16 + co];
        int rbase = 4 * (lane >> 5) + wid * 32;
        #pragma unroll
        for (int reg = 0; reg < 16; ++reg) {
            int q = rbase + (reg & 3) + 8 * (reg >> 2);
            if (q < nq) {
                int cc = q / 25, qp = q - cc * 25;
                float f = swishf(fmaf(acc2[reg], Ac, Bc));
                unsigned short hh = bf16_rne(f);
                unsigned short ll = bf16_rne(f - bf16_tof(hh));
                y2h16[cc * 808 + qp * 32 + co] = hh;
                y2l16[cc * 808 + qp * 32 + co] = ll;
            }
        }
    }
    __syncthreads();

    // conv3 MFMA 16x16x32: wave = Ntile, 25 steps in batches of 5
    {
        const uint4* w3f4 = (const uint4*)(wsu + OFF_W3F);
        f32x4 acc3 = {0.f, 0.f, 0.f, 0.f};
        for (int b5 = 0; b5 < 5; ++b5) {
            uint4 BH[5], BL[5];
            #pragma unroll
            for (int i = 0; i < 5; ++i) {
                int s = b5 * 5 + i;
                BH[i] = w3f4[((s * 4 + wid) * 2 + 0) * 64 + lane];
                BL[i] = w3f4[((s * 4 + wid) * 2 + 1) * 64 + lane];
            }
            #pragma unroll
            for (int i = 0; i < 5; ++i) {
                int s = b5 * 5 + i;
                bf16x8 ah = {}, al = {};
                if (li < tc) {
                    ah = *(const bf16x8*)(y2h16 + li * 808 + s * 32 + lg * 8);
                    al = *(const bf16x8*)(y2l16 + li * 808 + s * 32 + lg * 8);
                }
                bf16x8 bh = *(const bf16x8*)&BH[i];
                bf16x8 bl = *(const bf16x8*)&BL[i];
                acc3 = __builtin_amdgcn_mfma_f32_16x16x32_bf16(ah, bh, acc3, 0, 0, 0);
                acc3 = __builtin_amdgcn_mfma_f32_16x16x32_bf16(al, bh, acc3, 0, 0, 0);
                acc3 = __builtin_amdgcn_mfma_f32_16x16x32_bf16(ah, bl, acc3, 0, 0, 0);
            }
        }
        int co = wid * 16 + li;
        float A3 = A_s[48 + co], B3 = Bc_s[48 + co];
        unsigned int* featp = (unsigned int*)ws + OFF_FEAT;
        #pragma unroll
        for (int r = 0; r < 4; ++r) {
            int cc = lg * 4 + r;
            if (cc < tc)
                featp[((size_t)(seq * NCHUNK + tile * 5 + cc)) * 64 + co]
                    = pack_hl(swishf(fmaf(acc3[r], A3, B3)));
        }
    }
}

// One block per sequence. T' = F*Mh via MFMA (1 Ntile/wave); S = T'*F^T via
// MFMA reusing F A-frags as B-operand; wave0 overlaps softmax/colmean/fbar of
// head h-1 with head h's T'. Final: out = cbias' + concat_h(abar_h*F) * WC.
__global__ __launch_bounds__(256, 4) void mha_kernel(
    const float* __restrict__ ws, float* __restrict__ out, int B)
{
    __shared__ __align__(16) float smem[7872];
    unsigned int* f_p = (unsigned int*)smem;        // 32 x 68 packed (rows 22..31 zero)
    unsigned int* q_p = (unsigned int*)(smem + 2176); // 32 x 68 packed T' (rows 22..31 zero)
    float* f32F  = smem + 4352;  // 22 x 65
    float* s_s   = smem + 5782;  // 484
    float* abar  = smem + 6266;  // 22 (+2 pad)
    float* rowqc = smem + 6290;  // 8 x 22
    float* wh_s  = smem + 6466;  // 512
    float* fbar_s= smem + 6978;  // 512
    float* fred  = smem + 7490;  // 256

    int t = threadIdx.x, b = blockIdx.x;
    int lane = t & 63, wid = t >> 6;
    int li = lane & 15, lg = lane >> 4;
    const unsigned int* wsu = (const unsigned int*)ws;
    const unsigned int* featp = wsu + OFF_FEAT + (size_t)b * 1408;
    for (int i = t; i < 1408; i += 256) {
        unsigned int w = featp[i];
        int s = i >> 6, d = i & 63;
        f_p[s * 68 + d] = w;
        f32F[s * 65 + d] = __uint_as_float(w << 16) + __uint_as_float(w & 0xFFFF0000u);
    }
    for (int i = 1496 + t; i < 2176; i += 256) { f_p[i] = 0u; q_p[i] = 0u; }
    for (int i = t; i < 512; i += 256) wh_s[i] = ws[OFF_WH + i];
    __syncthreads();

    // F A-frags (also serve as B-frags of F^T)
    bf16x8 fah[2][2], fal[2][2];
    #pragma unroll
    for (int mt = 0; mt < 2; ++mt)
        #pragma unroll
        for (int ks = 0; ks < 2; ++ks)
            frag_from_packed(f_p + (mt * 16 + li) * 68 + ks * 32 + lg * 8,
                             fah[mt][ks], fal[mt][ks]);

    // rowqc[h][s] = F[s].u_h + c_h  (ready by the A(0) barrier)
    if (t < 176) {
        int h = t / 22, s = t - h * 22;
        float acc = ws[OFF_CH + h];
        const float* uh = ws + OFF_UH + h * 64;
        #pragma unroll 8
        for (int d = 0; d < 64; ++d) acc = fmaf(f32F[s * 65 + d], uh[d], acc);
        rowqc[t] = acc;
    }

    const uint4* mhf4 = (const uint4*)(wsu + OFF_MHF);
    int col = wid * 16 + li;
    uint4 n00 = mhf4[wid * 128 + lane];
    uint4 n01 = mhf4[wid * 128 + 64 + lane];
    uint4 n10 = mhf4[512 + wid * 128 + lane];
    uint4 n11 = mhf4[512 + wid * 128 + 64 + lane];

    for (int h = 0; h < 8; ++h) {
        if (wid == 0 && h > 0) {             // C(h-1): softmax + colmean + fbar
            int hp = h - 1;
            if (lane < 22) {
                float m = -1e30f;
                #pragma unroll
                for (int j = 0; j < 22; ++j) m = fmaxf(m, s_s[lane * 22 + j]);
                float sum = 0.f;
                #pragma unroll
                for (int j = 0; j < 22; ++j) { float ev = __expf(s_s[lane * 22 + j] - m); s_s[lane * 22 + j] = ev; sum += ev; }
                float rr = 1.f / sum;
                #pragma unroll
                for (int j = 0; j < 22; ++j) s_s[lane * 22 + j] *= rr;
            }
            if (lane < 22) {
                float a = 0.f;
                #pragma unroll
                for (int s = 0; s < 22; ++s) a += s_s[s * 22 + lane];
                abar[lane] = a * (1.f / 22.f);
            }
            {
                float acc = 0.f;
                #pragma unroll
                for (int u = 0; u < 22; ++u) acc = fmaf(abar[u], f32F[u * 65 + lane], acc);
                fbar_s[hp * 64 + lane] = acc;
            }
        }
        // A(h): T' = F * Mh, this wave's 16-col Ntile
        uint4 c00 = n00, c01 = n01, c10 = n10, c11 = n11;
        if (h < 7) {
            n00 = mhf4[(h + 1) * 1024 + wid * 128 + lane];
            n01 = mhf4[(h + 1) * 1024 + wid * 128 + 64 + lane];
            n10 = mhf4[(h + 1) * 1024 + 512 + wid * 128 + lane];
            n11 = mhf4[(h + 1) * 1024 + 512 + wid * 128 + 64 + lane];
        }
        f32x4 a0 = {0.f, 0.f, 0.f, 0.f}, a1 = a0;
        {
            bf16x8 bh = *(const bf16x8*)&c00, bl = *(const bf16x8*)&c01;
            a0 = __builtin_amdgcn_mfma_f32_16x16x32_bf16(fah[0][0], bh, a0, 0, 0, 0);
            a0 = __builtin_amdgcn_mfma_f32_16x16x32_bf16(fal[0][0], bh, a0, 0, 0, 0);
            a0 = __builtin_amdgcn_mfma_f32_16x16x32_bf16(fah[0][0], bl, a0, 0, 0, 0);
            a1 = __builtin_amdgcn_mfma_f32_16x16x32_bf16(fah[1][0], bh, a1, 0, 0, 0);
            a1 = __builtin_amdgcn_mfma_f32_16x16x32_bf16(fal[1][0], bh, a1, 0, 0, 0);
            a1 = __builtin_amdgcn_mfma_f32_16x16x32_bf16(fah[1][0], bl, a1, 0, 0, 0);
        }
        {
            bf16x8 bh = *(const bf16x8*)&c10, bl = *(const bf16x8*)&c11;
            a0 = __builtin_amdgcn_mfma_f32_16x16x32_bf16(fah[0][1], bh, a0, 0, 0, 0);
            a0 = __builtin_amdgcn_mfma_f32_16x16x32_bf16(fal[0][1], bh, a0, 0, 0, 0);
            a0 = __builtin_amdgcn_mfma_f32_16x16x32_bf16(fah[0][1], bl, a0, 0, 0, 0);
            a1 = __builtin_amdgcn_mfma_f32_16x16x32_bf16(fah[1][1], bh, a1, 0, 0, 0);
            a1 = __builtin_amdgcn_mfma_f32_16x16x32_bf16(fal[1][1], bh, a1, 0, 0, 0);
            a1 = __builtin_amdgcn_mfma_f32_16x16x32_bf16(fah[1][1], bl, a1, 0, 0, 0);
        }
        {
            float wv = wh_s[h * 64 + col];
            #pragma unroll
            for (int r = 0; r < 4; ++r) {
                int r0 = lg * 4 + r;
                q_p[r0 * 68 + col] = pack_hl(a0[r] + wv);
                int r1 = 16 + r0;
                if (r1 < 22) q_p[r1 * 68 + col] = pack_hl(a1[r] + wv);
            }
        }
        __syncthreads();
        // S(h) = T' * F^T via MFMA; wave quadrant (mt, ntile)
        {
            int mt = wid >> 1, ntile = wid & 1;
            f32x4 sacc = {0.f, 0.f, 0.f, 0.f};
            #pragma unroll
            for (int ks = 0; ks < 2; ++ks) {
                bf16x8 tqh, tql;
                frag_from_packed(q_p + (mt * 16 + li) * 68 + ks * 32 + lg * 8, tqh, tql);
                sacc = __builtin_amdgcn_mfma_f32_16x16x32_bf16(tqh, fah[ntile][ks], sacc, 0, 0, 0);
                sacc = __builtin_amdgcn_mfma_f32_16x16x32_bf16(tql, fah[ntile][ks], sacc, 0, 0, 0);
                sacc = __builtin_amdgcn_mfma_f32_16x16x32_bf16(tqh, fal[ntile][ks], sacc, 0, 0, 0);
            }
            int u = ntile * 16 + li;
            #pragma unroll
            for (int r = 0; r < 4; ++r) {
                int s = mt * 16 + lg * 4 + r;
                if (s < 22 && u < 22)
                    s_s[s * 22 + u] = sacc[r] + rowqc[h * 22 + s];
            }
        }
        __syncthreads();
    }
    if (wid == 0) {                          // C(7)
        if (lane < 22) {
            float m = -1e30f;
            #pragma unroll
            for (int j = 0; j < 22; ++j) m = fmaxf(m, s_s[lane * 22 + j]);
            float sum = 0.f;
            #pragma unroll
            for (int j = 0; j < 22; ++j) { float ev = __expf(s_s[lane * 22 + j] - m); s_s[lane * 22 + j] = ev; sum += ev; }
            float rr = 1.f / sum;
            #pragma unroll
            for (int j = 0; j < 22; ++j) s_s[lane * 22 + j] *= rr;
        }
        if (lane < 22) {
            float a = 0.f;
            #pragma unroll
            for (int s = 0; s < 22; ++s) a += s_s[s * 22 + lane];
            abar[lane] = a * (1.f / 22.f);
        }
        {
            float acc = 0.f;
            #pragma unroll
            for (int u = 0; u < 22; ++u) acc = fmaf(abar[u], f32F[u * 65 + lane], acc);
            fbar_s[7 * 64 + lane] = acc;
        }
    }
    __syncthreads();
    // out = cbias' + fbar(512) @ WC
    {
        int d = t & 63, part = t >> 6;
        const float* wc = ws + OFF_WC;
        float acc = 0.f;
        for (int j = part * 128; j < part * 128 + 128; ++j)
            acc = fmaf(fbar_s[j], wc[j * 64 + d], acc);
        fred[part * 64 + d] = acc;
    }
    __syncthreads();
    if (t < 64)
        out[(size_t)b * 64 + t] = ws[OFF_CBIAS + t]
            + fred[t] + fred[64 + t] + fred[128 + t] + fred[192 + t];
}

extern "C" void kernel_launch(void* const* d_in, const int* in_sizes, int n_in,
                              void* d_out, int out_size, void* d_ws, size_t ws_size,
                              hipStream_t stream) {
    const float* audio1 = (const float*)d_in[0];
    const float* audio2 = (const float*)d_in[1];
    const float* w1   = (const float*)d_in[2];
    const float* b1   = (const float*)d_in[3];
    const float* g1   = (const float*)d_in[4];
    const float* be1  = (const float*)d_in[5];
    const float* m1   = (const float*)d_in[6];
    const float* v1   = (const float*)d_in[7];
    const float* w2   = (const float*)d_in[8];
    const float* b2   = (const float*)d_in[9];
    const float* g2   = (const float*)d_in[10];
    const float* be2  = (const float*)d_in[11];
    const float* m2   = (const float*)d_in[12];
    const float* v2   = (const float*)d_in[13];
    const float* w3   = (const float*)d_in[14];
    const float* b3   = (const float*)d_in[15];
    const float* g3   = (const float*)d_in[16];
    const float* be3  = (const float*)d_in[17];
    const float* m3   = (const float*)d_in[18];
    const float* v3   = (const float*)d_in[19];
    const float* Wq   = (const float*)d_in[20];
    const float* bq   = (const float*)d_in[21];
    const float* Wk   = (const float*)d_in[22];
    const float* bk   = (const float*)d_in[23];
    const float* Wv   = (const float*)d_in[24];
    const float* bv   = (const float*)d_in[25];
    const float* Wfc  = (const float*)d_in[26];
    const float* bfc  = (const float*)d_in[27];
    const float* Wout = (const float*)d_in[28];
    const float* bout = (const float*)d_in[29];

    float* ws  = (float*)d_ws;
    float* out = (float*)d_out;
    int B = in_sizes[0] / SEQLEN;   // 4096
    int nseq = 2 * B;

    repack_kernel<<<(REPACK_N + 255) / 256, 256, 0, stream>>>(
        w1, w2, w3, Wq, Wk, Wv, Wfc, Wout, bq, bk, ws);
    cbias_kernel<<<1, 64, 0, stream>>>(Wfc, Wout, bfc, bout, bv, ws);
    encoder_kernel<<<nseq * 5, 256, 0, stream>>>(audio1, audio2,
        b1, g1, be1, m1, v1,
        b2, g2, be2, m2, v2,
        b3, g3, be3, m3, v3,
        ws, B);
    mha_kernel<<<nseq, 256, 0, stream>>>(ws, out, B);
}

// Round 9
// 863.130 us; speedup vs baseline: 1.7705x; 1.3075x over previous
//
#include <hip/hip_runtime.h>
#include <math.h>

#define NCHUNK 22
#define SEQLEN 600
#define BN_EPS 1e-5f

// ws offsets (4-byte units)
#define OFF_W1F    0         // 1024   u32 : conv1 B dup-frags [ph2][pat2][lane][r]
#define OFF_W2F    1024      // 13312  u32 : conv2 32x32 B-frags [s26][hl2][lane][r4]
#define OFF_W3F    14336     // 51200  u32 : conv3 B-frags [s25][nt4][hl2][lane][r4]
#define OFF_MHF    65536     // 32768  u32 : Mh=WqT*Wk B-frags [h8][ks2][nt4][hl2][lane][r4]
#define OFF_WC     98304     // 32768  f32 : WC (final, by repack2)
#define OFF_UH     131072    // 512    f32 : u_h[h][d] = sum_e Wq[h,e,d]*bk[h,e]
#define OFF_WH     131584    // 512    f32 : w_h[h][d] = sum_e Wk[h,e,d]*bq[h,e]
#define OFF_CH     132096    // 8      f32 : c_h = bq.bk
#define OFF_CBIAS  132104    // 64     f32 : all-bias fold (cbias kernel)
#define OFF_WCOMB  132168    // 32768  f32 : Wcomb intermediate (repack)
#define OFF_FEAT   164936    // 2*B*22*64 u32 (PACKED hi|lo)
#define REPACK_N   132104

typedef short bf16x8 __attribute__((ext_vector_type(8)));
typedef float f32x4 __attribute__((ext_vector_type(4)));
typedef float f32x16 __attribute__((ext_vector_type(16)));

#if __has_builtin(__builtin_amdgcn_perm)
#define PERM_HI(r0, r1) __builtin_amdgcn_perm((r1), (r0), 0x05040100u)
#define PERM_LO(r0, r1) __builtin_amdgcn_perm((r1), (r0), 0x07060302u)
#else
#define PERM_HI(r0, r1) (((r0) & 0xFFFFu) | ((r1) << 16))
#define PERM_LO(r0, r1) (((r0) >> 16) | ((r1) & 0xFFFF0000u))
#endif

__device__ __forceinline__ float swishf(float z) {
    return z / (1.f + __expf(-z));
}
__device__ __forceinline__ unsigned short bf16_rne(float f) {
    unsigned int u = __float_as_uint(f);
    return (unsigned short)((u + 0x7FFFu + ((u >> 16) & 1u)) >> 16);
}
__device__ __forceinline__ float bf16_tof(unsigned short h) {
    return __uint_as_float(((unsigned int)h) << 16);
}
// packed u32: low16 = hi-bf16, high16 = lo-bf16 (residual)
__device__ __forceinline__ unsigned int pack_hl(float f) {
    unsigned int u = __float_as_uint(f);
    unsigned int h = (u + 0x7FFFu + ((u >> 16) & 1u)) >> 16;
    float r = f - __uint_as_float(h << 16);
    unsigned int v = __float_as_uint(r);
    unsigned int l = (v + 0x7FFFu + ((v >> 16) & 1u)) >> 16;
    return h | (l << 16);
}
__device__ __forceinline__ unsigned int dup_word(float f, int pat) {
    unsigned short h = bf16_rne(f);
    unsigned short v = pat ? bf16_rne(f - bf16_tof(h)) : h;
    return (unsigned int)v | ((unsigned int)v << 16);
}
__device__ __forceinline__ unsigned int frag_word(float f0, float f1, int hl) {
    unsigned short h0 = bf16_rne(f0), h1 = bf16_rne(f1);
    if (hl == 0) return (unsigned int)h0 | ((unsigned int)h1 << 16);
    unsigned short l0 = bf16_rne(f0 - bf16_tof(h0));
    unsigned short l1 = bf16_rne(f1 - bf16_tof(h1));
    return (unsigned int)l0 | ((unsigned int)l1 << 16);
}
__device__ __forceinline__ void frag_from_packed(const unsigned int* p, bf16x8& h8, bf16x8& l8) {
    unsigned int r0 = p[0], r1 = p[1], r2 = p[2], r3 = p[3];
    unsigned int r4 = p[4], r5 = p[5], r6 = p[6], r7 = p[7];
    union U { unsigned int w[4]; bf16x8 v; } H, L;
    H.w[0] = PERM_HI(r0, r1); H.w[1] = PERM_HI(r2, r3);
    H.w[2] = PERM_HI(r4, r5); H.w[3] = PERM_HI(r6, r7);
    L.w[0] = PERM_LO(r0, r1); L.w[1] = PERM_LO(r2, r3);
    L.w[2] = PERM_LO(r4, r5); L.w[3] = PERM_LO(r6, r7);
    h8 = H.v; l8 = L.v;
}

__global__ __launch_bounds__(256) void repack_kernel(
    const float* __restrict__ w1, const float* __restrict__ w2, const float* __restrict__ w3,
    const float* __restrict__ Wq, const float* __restrict__ Wk, const float* __restrict__ Wv,
    const float* __restrict__ Wfc, const float* __restrict__ Wout,
    const float* __restrict__ bq, const float* __restrict__ bk,
    float* __restrict__ ws)
{
    int tid = blockIdx.x * 256 + threadIdx.x;
    unsigned int* wsu = (unsigned int*)ws;
    if (tid < 1024) {                        // conv1 dup-B
        int r = tid & 3, lane = (tid >> 2) & 63, pat = (tid >> 8) & 1, ph = (tid >> 9) & 1;
        int li = lane & 15, lg = lane >> 4;
        int k = ph * 16 + lg * 4 + r;
        float f = (k < 26) ? w1[li * 26 + k] : 0.f;
        wsu[OFF_W1F + tid] = dup_word(f, pat);
    }
    int t2 = tid - 1024;
    if (t2 >= 0 && t2 < 13312) {             // conv2 32x32x16 B-frags
        int r = t2 & 3, lane = (t2 >> 2) & 63, hl = (t2 >> 8) & 1, s = t2 >> 9;
        int co = lane & 31;
        int ci0 = (lane >> 5) * 8;
        float f0 = w2[co * 416 + (ci0 + 2 * r) * 26 + s];
        float f1 = w2[co * 416 + (ci0 + 2 * r + 1) * 26 + s];
        wsu[OFF_W2F + t2] = frag_word(f0, f1, hl);
    }
    int t3 = tid - 14336;
    if (t3 >= 0 && t3 < 51200) {             // conv3 B-frags
        int r = t3 & 3, l = (t3 >> 2) & 63, hl = (t3 >> 8) & 1;
        int nt = (t3 >> 9) & 3, s = t3 >> 11;
        int co = nt * 16 + (l & 15);
        int k0 = s * 32 + (l >> 4) * 8 + 2 * r;
        float f0 = w3[co * 800 + (k0 & 31) * 25 + (k0 >> 5)];
        float f1 = w3[co * 800 + ((k0 + 1) & 31) * 25 + ((k0 + 1) >> 5)];
        wsu[OFF_W3F + t3] = frag_word(f0, f1, hl);
    }
    int t4 = tid - 65536;
    if (t4 >= 0 && t4 < 32768) {             // Mh B-frags
        int r = t4 & 3, l = (t4 >> 2) & 63, hl = (t4 >> 8) & 1;
        int nt = (t4 >> 9) & 3, ks = (t4 >> 11) & 1, h = t4 >> 12;
        int n = nt * 16 + (l & 15);
        int d0 = ks * 32 + (l >> 4) * 8 + 2 * r;
        const float* wqh = Wq + h * 4096;
        const float* wkh = Wk + h * 4096;
        float f0 = 0.f, f1 = 0.f;
        #pragma unroll 8
        for (int e = 0; e < 64; ++e) {
            float wk_en = wkh[e * 64 + n];
            f0 = fmaf(wqh[e * 64 + d0],     wk_en, f0);
            f1 = fmaf(wqh[e * 64 + d0 + 1], wk_en, f1);
        }
        wsu[OFF_MHF + t4] = frag_word(f0, f1, hl);
    }
    int t7 = tid - 98304;
    if (t7 >= 0 && t7 < 32768) {             // Wcomb[j][k] intermediate
        int k = t7 & 63, j = t7 >> 6;
        float acc = 0.f;
        #pragma unroll 8
        for (int d = 0; d < 64; ++d)
            acc = fmaf(Wfc[d * 512 + j], Wout[k * 64 + d], acc);
        ws[OFF_WCOMB + t7] = acc;
    }
    int t8 = tid - 131072;
    if (t8 >= 0 && t8 < 512) {               // u_h
        int h = t8 >> 6, d = t8 & 63;
        float acc = 0.f;
        #pragma unroll 8
        for (int e = 0; e < 64; ++e) acc = fmaf(Wq[h * 4096 + e * 64 + d], bk[h * 64 + e], acc);
        ws[OFF_UH + t8] = acc;
    }
    int t9 = tid - 131584;
    if (t9 >= 0 && t9 < 512) {               // w_h
        int h = t9 >> 6, d = t9 & 63;
        float acc = 0.f;
        #pragma unroll 8
        for (int e = 0; e < 64; ++e) acc = fmaf(Wk[h * 4096 + e * 64 + d], bq[h * 64 + e], acc);
        ws[OFF_WH + t9] = acc;
    }
    int t10 = tid - 132096;
    if (t10 >= 0 && t10 < 8) {               // c_h
        float acc = 0.f;
        #pragma unroll 8
        for (int e = 0; e < 64; ++e) acc = fmaf(bq[t10 * 64 + e], bk[t10 * 64 + e], acc);
        ws[OFF_CH + t10] = acc;
    }
}

// WC[h*64+d][k] = sum_e Wv[h,e,d] * Wcomb[(h*64+e)][k]  (Wv reads wave-uniform)
__global__ __launch_bounds__(256) void repack2_kernel(
    const float* __restrict__ Wv, float* __restrict__ ws)
{
    int tid = blockIdx.x * 256 + threadIdx.x;   // 32768
    int k = tid & 63, j = tid >> 6;
    int h = j >> 6, d = j & 63;
    const float* wcomb = ws + OFF_WCOMB + (size_t)(h * 64) * 64 + k;
    const float* wv = Wv + h * 4096 + d;
    float acc = 0.f;
    #pragma unroll 8
    for (int e = 0; e < 64; ++e)
        acc = fmaf(wv[e * 64], wcomb[e * 64], acc);
    ws[OFF_WC + tid] = acc;
}

// cbias'[k] = bout[k] + sum_dp (bfc[dp] + sum_j bv[j]*Wfc[dp][j]) * Wout[k][dp]
__global__ __launch_bounds__(64) void cbias_kernel(
    const float* __restrict__ Wfc, const float* __restrict__ Wout,
    const float* __restrict__ bfc, const float* __restrict__ bout,
    const float* __restrict__ bv, float* __restrict__ ws)
{
    __shared__ float sd_s[64];
    int t = threadIdx.x;
    float acc = 0.f;
    for (int j = 0; j < 512; ++j) acc = fmaf(bv[j], Wfc[t * 512 + j], acc);
    sd_s[t] = acc;
    __syncthreads();
    float cb = bout[t];
    #pragma unroll 8
    for (int dp = 0; dp < 64; ++dp) cb = fmaf(bfc[dp] + sd_s[dp], Wout[t * 64 + dp], cb);
    ws[OFF_CBIAS + t] = cb;
}

// Encoder (R7/R8-proven structure) with y2 ALIASED over y1 (dead after conv2's
// final barrier) -> LDS 26 KB -> 6 blocks/CU.
__global__ __launch_bounds__(256, 6) void encoder_kernel(
    const float* __restrict__ audio1, const float* __restrict__ audio2,
    const float* __restrict__ b1, const float* __restrict__ g1, const float* __restrict__ be1,
    const float* __restrict__ m1, const float* __restrict__ v1,
    const float* __restrict__ b2, const float* __restrict__ g2, const float* __restrict__ be2,
    const float* __restrict__ m2, const float* __restrict__ v2,
    const float* __restrict__ b3, const float* __restrict__ g3, const float* __restrict__ be3,
    const float* __restrict__ m3, const float* __restrict__ v3,
    float* __restrict__ ws, int B)
{
    __shared__ __align__(16) unsigned int smem[6504];
    unsigned int* a_p = smem;                              // [0,192)
    unsigned int* w2f = smem + 192;                        // [192,2240) 2x1024 dbuf
    unsigned short* y1h16 = (unsigned short*)(smem + 2240);// [2240,3780) 154x20 u16
    unsigned short* y1l16 = (unsigned short*)(smem + 3780);// [3780,5320)
    unsigned short* y2h16 = (unsigned short*)(smem + 2240);// ALIAS: [2240,4260) 5x808 u16
    unsigned short* y2l16 = (unsigned short*)(smem + 4260);// [4260,6280)
    float* A_s  = (float*)(smem + 6280);                   // 112
    float* Bc_s = (float*)(smem + 6392);                   // 112

    int t = threadIdx.x;
    int blk = blockIdx.x;
    int seq = blk / 5, tile = blk - seq * 5;
    int tc = (tile == 4) ? 2 : 5;
    int nq = 25 * tc;
    int ny1 = nq + 25;
    int na = nq + 50;
    const unsigned int* wsu = (const unsigned int*)ws;
    int lane = t & 63, wid = t >> 6;
    int li = lane & 15, lg = lane >> 4;

    const float* audio = (seq < B ? audio1 + (size_t)seq * SEQLEN
                                  : audio2 + (size_t)(seq - B) * SEQLEN) + tile * 125;
    uint4 w1b[2][2];
    #pragma unroll
    for (int ph = 0; ph < 2; ++ph)
        #pragma unroll
        for (int pat = 0; pat < 2; ++pat)
            w1b[ph][pat] = *(const uint4*)(wsu + OFF_W1F + ((ph * 2 + pat) * 64 + lane) * 4);

    if (t < 192) a_p[t] = (t < na) ? pack_hl(audio[t]) : 0u;
    *(uint4*)(w2f + t * 4) = *(const uint4*)(wsu + OFF_W2F + t * 4);
    if (t < 16)       { float A = g1[t] * rsqrtf(v1[t] + BN_EPS); A_s[t] = A; Bc_s[t] = (b1[t] - m1[t]) * A + be1[t]; }
    else if (t < 48)  { int i = t - 16; float A = g2[i] * rsqrtf(v2[i] + BN_EPS); A_s[t] = A; Bc_s[t] = (b2[i] - m2[i]) * A + be2[i]; }
    else if (t < 112) { int i = t - 48; float A = g3[i] * rsqrtf(v3[i] + BN_EPS); A_s[t] = A; Bc_s[t] = (b3[i] - m3[i]) * A + be3[i]; }
    for (int i = ny1 * 10 + t; i < 1540; i += 256) {
        (smem + 2240)[i] = 0u;
        (smem + 3780)[i] = 0u;
    }
    __syncthreads();

    // conv1 MFMA (dup-B)
    {
        int nMt1 = (ny1 + 15) >> 4;
        float Ai = A_s[li], Bi = Bc_s[li];
        for (int mt = wid; mt < nMt1; mt += 4) {
            f32x4 acc = {0.f, 0.f, 0.f, 0.f};
            #pragma unroll
            for (int ph = 0; ph < 2; ++ph) {
                const unsigned int* ap = a_p + mt * 16 + li + ph * 16 + lg * 4;
                union { unsigned int w[4]; bf16x8 v; } A;
                A.w[0] = ap[0]; A.w[1] = ap[1]; A.w[2] = ap[2]; A.w[3] = ap[3];
                bf16x8 b0 = *(const bf16x8*)&w1b[ph][0];
                bf16x8 b1 = *(const bf16x8*)&w1b[ph][1];
                acc = __builtin_amdgcn_mfma_f32_16x16x32_bf16(A.v, b0, acc, 0, 0, 0);
                acc = __builtin_amdgcn_mfma_f32_16x16x32_bf16(A.v, b1, acc, 0, 0, 0);
            }
            #pragma unroll
            for (int r = 0; r < 4; ++r) {
                int p = mt * 16 + lg * 4 + r;
                if (p < ny1) {
                    float f = swishf(fmaf(acc[r], Ai, Bi));
                    unsigned short hh = bf16_rne(f);
                    unsigned short ll = bf16_rne(f - bf16_tof(hh));
                    y1h16[p * 20 + li] = hh;
                    y1l16[p * 20 + li] = ll;
                }
            }
        }
    }
    __syncthreads();

    // conv2 MFMA 32x32x16, two-plane A
    int row0 = wid * 32 + (lane & 31);
    int ci0 = (lane >> 5) * 8;
    f32x16 acc2;
    #pragma unroll
    for (int r = 0; r < 16; ++r) acc2[r] = 0.f;

    for (int stg = 0; stg < 13; ++stg) {
        uint4 vnext;
        if (stg < 12)
            vnext = *(const uint4*)(wsu + OFF_W2F + (stg + 1) * 1024 + t * 4);
        const unsigned int* cur = w2f + (stg & 1) * 1024;
        #pragma unroll
        for (int half = 0; half < 2; ++half) {
            int s = stg * 2 + half;
            bf16x8 bh = *(const bf16x8*)(cur + half * 512 + lane * 4);
            bf16x8 bl = *(const bf16x8*)(cur + half * 512 + 256 + lane * 4);
            const unsigned short* hp = y1h16 + (row0 + s) * 20 + ci0;
            const unsigned short* lp = y1l16 + (row0 + s) * 20 + ci0;
            union { uint2 u[2]; bf16x8 v; } Ah, Al;
            Ah.u[0] = *(const uint2*)hp; Ah.u[1] = *(const uint2*)(hp + 4);
            Al.u[0] = *(const uint2*)lp; Al.u[1] = *(const uint2*)(lp + 4);
            acc2 = __builtin_amdgcn_mfma_f32_32x32x16_bf16(Ah.v, bh, acc2, 0, 0, 0);
            acc2 = __builtin_amdgcn_mfma_f32_32x32x16_bf16(Al.v, bh, acc2, 0, 0, 0);
            acc2 = __builtin_amdgcn_mfma_f32_32x32x16_bf16(Ah.v, bl, acc2, 0, 0, 0);
        }
        if (stg < 12)
            *(uint4*)(w2f + ((stg + 1) & 1) * 1024 + t * 4) = vnext;
        __syncthreads();
    }
    // epilogue writes y2 (aliases y1; all y1 reads completed at the final barrier)
    {
        int co = lane & 31;
        float Ac = A_s[16 + co], Bc = Bc_s[16 + co];
        int rbase = 4 * (lane >> 5) + wid * 32;
        #pragma unroll
        for (int reg = 0; reg < 16; ++reg) {
            int q = rbase + (reg & 3) + 8 * (reg >> 2);
            if (q < nq) {
                int cc = q / 25, qp = q - cc * 25;
                float f = swishf(fmaf(acc2[reg], Ac, Bc));
                unsigned short hh = bf16_rne(f);
                unsigned short ll = bf16_rne(f - bf16_tof(hh));
                y2h16[cc * 808 + qp * 32 + co] = hh;
                y2l16[cc * 808 + qp * 32 + co] = ll;
            }
        }
    }
    __syncthreads();

    // conv3 MFMA 16x16x32: wave = Ntile, 25 steps in batches of 5
    {
        const uint4* w3f4 = (const uint4*)(wsu + OFF_W3F);
        f32x4 acc3 = {0.f, 0.f, 0.f, 0.f};
        for (int b5 = 0; b5 < 5; ++b5) {
            uint4 BH[5], BL[5];
            #pragma unroll
            for (int i = 0; i < 5; ++i) {
                int s = b5 * 5 + i;
                BH[i] = w3f4[((s * 4 + wid) * 2 + 0) * 64 + lane];
                BL[i] = w3f4[((s * 4 + wid) * 2 + 1) * 64 + lane];
            }
            #pragma unroll
            for (int i = 0; i < 5; ++i) {
                int s = b5 * 5 + i;
                bf16x8 ah = {}, al = {};
                if (li < tc) {
                    ah = *(const bf16x8*)(y2h16 + li * 808 + s * 32 + lg * 8);
                    al = *(const bf16x8*)(y2l16 + li * 808 + s * 32 + lg * 8);
                }
                bf16x8 bh = *(const bf16x8*)&BH[i];
                bf16x8 bl = *(const bf16x8*)&BL[i];
                acc3 = __builtin_amdgcn_mfma_f32_16x16x32_bf16(ah, bh, acc3, 0, 0, 0);
                acc3 = __builtin_amdgcn_mfma_f32_16x16x32_bf16(al, bh, acc3, 0, 0, 0);
                acc3 = __builtin_amdgcn_mfma_f32_16x16x32_bf16(ah, bl, acc3, 0, 0, 0);
            }
        }
        int co = wid * 16 + li;
        float A3 = A_s[48 + co], B3 = Bc_s[48 + co];
        unsigned int* featp = (unsigned int*)ws + OFF_FEAT;
        #pragma unroll
        for (int r = 0; r < 4; ++r) {
            int cc = lg * 4 + r;
            if (cc < tc)
                featp[((size_t)(seq * NCHUNK + tile * 5 + cc)) * 64 + co]
                    = pack_hl(swishf(fmaf(acc3[r], A3, B3)));
        }
    }
}

// One block per sequence; each WAVE independently owns 2 heads end-to-end
// (T' -> S -> lane-parallel softmax/colmean/fbar). Zero barriers in head loop.
// Fragment reads past row 21 hit garbage that only feeds never-stored D rows.
__global__ __launch_bounds__(256, 3) void mha_kernel(
    const float* __restrict__ ws, float* __restrict__ out, int B)
{
    __shared__ __align__(16) unsigned int smem[12398];
    unsigned int* f_p = smem;                         // [0,1496)    22x68
    // q_p per wave: base 1496 + w*1496, 22x68 (frag reads overflow harmlessly)
    float* f32F   = (float*)(smem + 7480);            // 22x65
    // s_s per wave: base 8910 + w*484
    // abar scratch per wave: base 10846 + w*24
    float* rowqc  = (float*)(smem + 10942);           // per wave base + w*44
    float* wh_s   = (float*)(smem + 11118);           // 512
    float* fbar_s = (float*)(smem + 11630);           // 512
    float* fred   = (float*)(smem + 12142);           // 256

    int t = threadIdx.x, b = blockIdx.x;
    int lane = t & 63, wid = t >> 6;
    int li = lane & 15, lg = lane >> 4;
    const unsigned int* wsu = (const unsigned int*)ws;
    const unsigned int* featp = wsu + OFF_FEAT + (size_t)b * 1408;
    for (int i = t; i < 1408; i += 256) {
        unsigned int w = featp[i];
        int s = i >> 6, d = i & 63;
        f_p[s * 68 + d] = w;
        f32F[s * 65 + d] = __uint_as_float(w << 16) + __uint_as_float(w & 0xFFFF0000u);
    }
    for (int i = t; i < 512; i += 256) wh_s[i] = ws[OFF_WH + i];
    __syncthreads();

    unsigned int* q_pw = smem + 1496 + wid * 1496;
    float* P      = (float*)(smem + 8910) + wid * 484;
    float* abar_w = (float*)(smem + 10846) + wid * 24;
    float* rowq_w = rowqc + wid * 44;

    // per-wave rowqc for this wave's 2 heads: rowq_w[hl*22+s] = F[s].u_h + c_h
    if (lane < 44) {
        int hl = lane / 22, s = lane - hl * 22;
        int h = wid * 2 + hl;
        float acc = ws[OFF_CH + h];
        const float* uh = ws + OFF_UH + h * 64;
        #pragma unroll 8
        for (int d = 0; d < 64; ++d) acc = fmaf(f32F[s * 65 + d], uh[d], acc);
        rowq_w[lane] = acc;
    }

    // F A-frags (also the B-frags of F^T)
    bf16x8 fah[2][2], fal[2][2];
    #pragma unroll
    for (int mt = 0; mt < 2; ++mt)
        #pragma unroll
        for (int ks = 0; ks < 2; ++ks)
            frag_from_packed(f_p + (mt * 16 + li) * 68 + ks * 32 + lg * 8,
                             fah[mt][ks], fal[mt][ks]);

    const uint4* mhf4 = (const uint4*)(wsu + OFF_MHF);

    #pragma unroll
    for (int hh = 0; hh < 2; ++hh) {
        int h = wid * 2 + hh;
        // ---- T' = F @ Mh : all 4 Ntiles in this wave ----
        f32x4 a0t0 = {0,0,0,0}, a0t1 = a0t0, a0t2 = a0t0, a0t3 = a0t0;
        f32x4 a1t0 = a0t0, a1t1 = a0t0, a1t2 = a0t0, a1t3 = a0t0;
        #pragma unroll
        for (int nt = 0; nt < 4; ++nt) {
            f32x4 r0 = {0,0,0,0}, r1 = {0,0,0,0};
            #pragma unroll
            for (int ks = 0; ks < 2; ++ks) {
                uint4 bh4 = mhf4[h * 1024 + ks * 512 + nt * 128 + lane];
                uint4 bl4 = mhf4[h * 1024 + ks * 512 + nt * 128 + 64 + lane];
                bf16x8 bh = *(const bf16x8*)&bh4;
                bf16x8 bl = *(const bf16x8*)&bl4;
                r0 = __builtin_amdgcn_mfma_f32_16x16x32_bf16(fah[0][ks], bh, r0, 0, 0, 0);
                r0 = __builtin_amdgcn_mfma_f32_16x16x32_bf16(fal[0][ks], bh, r0, 0, 0, 0);
                r0 = __builtin_amdgcn_mfma_f32_16x16x32_bf16(fah[0][ks], bl, r0, 0, 0, 0);
                r1 = __builtin_amdgcn_mfma_f32_16x16x32_bf16(fah[1][ks], bh, r1, 0, 0, 0);
                r1 = __builtin_amdgcn_mfma_f32_16x16x32_bf16(fal[1][ks], bh, r1, 0, 0, 0);
                r1 = __builtin_amdgcn_mfma_f32_16x16x32_bf16(fah[1][ks], bl, r1, 0, 0, 0);
            }
            if (nt == 0) { a0t0 = r0; a1t0 = r1; }
            else if (nt == 1) { a0t1 = r0; a1t1 = r1; }
            else if (nt == 2) { a0t2 = r0; a1t2 = r1; }
            else { a0t3 = r0; a1t3 = r1; }
        }
        // epilogue -> q_pw packed (rows < 22 only)
        #pragma unroll
        for (int nt = 0; nt < 4; ++nt) {
            int col = nt * 16 + li;
            float wv = wh_s[h * 64 + col];
            f32x4 r0 = (nt == 0) ? a0t0 : (nt == 1) ? a0t1 : (nt == 2) ? a0t2 : a0t3;
            f32x4 r1 = (nt == 0) ? a1t0 : (nt == 1) ? a1t1 : (nt == 2) ? a1t2 : a1t3;
            #pragma unroll
            for (int r = 0; r < 4; ++r) {
                int row0 = lg * 4 + r;
                q_pw[row0 * 68 + col] = pack_hl(r0[r] + wv);
                int row1 = 16 + row0;
                if (row1 < 22) q_pw[row1 * 68 + col] = pack_hl(r1[r] + wv);
            }
        }
        // ---- S = T' @ F^T : 4 quadrants in this wave ----
        #pragma unroll
        for (int mt = 0; mt < 2; ++mt) {
            bf16x8 tqh0, tql0, tqh1, tql1;
            frag_from_packed(q_pw + (mt * 16 + li) * 68 + 0 * 32 + lg * 8, tqh0, tql0);
            frag_from_packed(q_pw + (mt * 16 + li) * 68 + 1 * 32 + lg * 8, tqh1, tql1);
            #pragma unroll
            for (int ntile = 0; ntile < 2; ++ntile) {
                f32x4 sacc = {0, 0, 0, 0};
                sacc = __builtin_amdgcn_mfma_f32_16x16x32_bf16(tqh0, fah[ntile][0], sacc, 0, 0, 0);
                sacc = __builtin_amdgcn_mfma_f32_16x16x32_bf16(tql0, fah[ntile][0], sacc, 0, 0, 0);
                sacc = __builtin_amdgcn_mfma_f32_16x16x32_bf16(tqh0, fal[ntile][0], sacc, 0, 0, 0);
                sacc = __builtin_amdgcn_mfma_f32_16x16x32_bf16(tqh1, fah[ntile][1], sacc, 0, 0, 0);
                sacc = __builtin_amdgcn_mfma_f32_16x16x32_bf16(tql1, fah[ntile][1], sacc, 0, 0, 0);
                sacc = __builtin_amdgcn_mfma_f32_16x16x32_bf16(tqh1, fal[ntile][1], sacc, 0, 0, 0);
                int u = ntile * 16 + li;
                #pragma unroll
                for (int r = 0; r < 4; ++r) {
                    int s = mt * 16 + lg * 4 + r;
                    if (s < 22 && u < 22)
                        P[s * 22 + u] = sacc[r] + rowq_w[hh * 22 + s];
                }
            }
        }
        // ---- C: lane-parallel softmax + weighted colmean + fbar ----
        {
            int r2 = lane >> 1, c2 = lane & 1;        // lane<44: row r2, half c2
            float pm = -1e30f, psum = 0.f;
            if (lane < 44) {
                #pragma unroll
                for (int j = 0; j < 11; ++j) pm = fmaxf(pm, P[r2 * 22 + c2 * 11 + j]);
            }
            float m = fmaxf(__shfl(pm, 2 * lane), __shfl(pm, 2 * lane + 1)); // lane<22
            float rm = __shfl(m, r2);
            if (lane < 44) {
                #pragma unroll
                for (int j = 0; j < 11; ++j) {
                    int idx = r2 * 22 + c2 * 11 + j;
                    float ev = __expf(P[idx] - rm);
                    P[idx] = ev;
                    psum += ev;
                }
            }
            float sum = __shfl(psum, 2 * lane) + __shfl(psum, 2 * lane + 1);  // lane<22
            if (lane < 22) abar_w[lane] = 1.f / sum;                          // rinv
            if (lane < 22) {
                float a = 0.f;
                #pragma unroll
                for (int s = 0; s < 22; ++s) a += P[s * 22 + lane] * abar_w[s];
                abar_w[lane] = a * (1.f / 22.f);       // lockstep: all reads precede writes
            }
            float acc = 0.f;
            #pragma unroll
            for (int u = 0; u < 22; ++u) acc = fmaf(abar_w[u], f32F[u * 65 + lane], acc);
            fbar_s[h * 64 + lane] = acc;
        }
    }
    __syncthreads();
    // out = cbias' + fbar(512) @ WC
    {
        int d = t & 63, part = t >> 6;
        const float* wc = ws + OFF_WC;
        float acc = 0.f;
        for (int j = part * 128; j < part * 128 + 128; ++j)
            acc = fmaf(fbar_s[j], wc[j * 64 + d], acc);
        fred[part * 64 + d] = acc;
    }
    __syncthreads();
    if (t < 64)
        out[(size_t)b * 64 + t] = ws[OFF_CBIAS + t]
            + fred[t] + fred[64 + t] + fred[128 + t] + fred[192 + t];
}

extern "C" void kernel_launch(void* const* d_in, const int* in_sizes, int n_in,
                              void* d_out, int out_size, void* d_ws, size_t ws_size,
                              hipStream_t stream) {
    const float* audio1 = (const float*)d_in[0];
    const float* audio2 = (const float*)d_in[1];
    const float* w1   = (const float*)d_in[2];
    const float* b1   = (const float*)d_in[3];
    const float* g1   = (const float*)d_in[4];
    const float* be1  = (const float*)d_in[5];
    const float* m1   = (const float*)d_in[6];
    const float* v1   = (const float*)d_in[7];
    const float* w2   = (const float*)d_in[8];
    const float* b2   = (const float*)d_in[9];
    const float* g2   = (const float*)d_in[10];
    const float* be2  = (const float*)d_in[11];
    const float* m2   = (const float*)d_in[12];
    const float* v2   = (const float*)d_in[13];
    const float* w3   = (const float*)d_in[14];
    const float* b3   = (const float*)d_in[15];
    const float* g3   = (const float*)d_in[16];
    const float* be3  = (const float*)d_in[17];
    const float* m3   = (const float*)d_in[18];
    const float* v3   = (const float*)d_in[19];
    const float* Wq   = (const float*)d_in[20];
    const float* bq   = (const float*)d_in[21];
    const float* Wk   = (const float*)d_in[22];
    const float* bk   = (const float*)d_in[23];
    const float* Wv   = (const float*)d_in[24];
    const float* bv   = (const float*)d_in[25];
    const float* Wfc  = (const float*)d_in[26];
    const float* bfc  = (const float*)d_in[27];
    const float* Wout = (const float*)d_in[28];
    const float* bout = (const float*)d_in[29];

    float* ws  = (float*)d_ws;
    float* out = (float*)d_out;
    int B = in_sizes[0] / SEQLEN;   // 4096
    int nseq = 2 * B;

    repack_kernel<<<(REPACK_N + 255) / 256, 256, 0, stream>>>(
        w1, w2, w3, Wq, Wk, Wv, Wfc, Wout, bq, bk, ws);
    repack2_kernel<<<128, 256, 0, stream>>>(Wv, ws);
    cbias_kernel<<<1, 64, 0, stream>>>(Wfc, Wout, bfc, bout, bv, ws);
    encoder_kernel<<<nseq * 5, 256, 0, stream>>>(audio1, audio2,
        b1, g1, be1, m1, v1,
        b2, g2, be2, m2, v2,
        b3, g3, be3, m3, v3,
        ws, B);
    mha_kernel<<<nseq, 256, 0, stream>>>(ws, out, B);
}